// Round 6
// baseline (3088.782 us; speedup 1.0000x reference)
//
#include <hip/hip_runtime.h>
#include <math.h>

// ---- problem constants ----
constexpr int CB = 8, CNT = 64, CD = 256, CKSEL = 16;
constexpr int CNH = 8, CNL = 4, CNP = 4, CDH = 32;
constexpr int CP = 12288, CS = 16320, CQ = 1024, CBQ = 8192, CDFF = 1024;

// ================= top-k =================
__global__ __launch_bounds__(256) void topk_kernel(const float* __restrict__ c_t,
                                                   float* __restrict__ p_patch,
                                                   float* __restrict__ ref) {
  const int bt = blockIdx.x;  // b*64 + t
  const float* row = c_t + (size_t)bt * CP;
  const int tid = threadIdx.x;
  float lv[16]; int li[16];
#pragma unroll
  for (int j = 0; j < 16; ++j) { lv[j] = -INFINITY; li[j] = 0x7fffffff; }
  for (int s = tid; s < CP; s += 256) {
    float v = row[s];
    if (v > lv[15]) {       // tie keeps earlier (lower) index: strict >
      lv[15] = v; li[15] = s;
#pragma unroll
      for (int j = 15; j > 0; --j) {   // bubble up; all indices compile-time
        if (lv[j] > lv[j - 1]) {
          float tv = lv[j]; lv[j] = lv[j - 1]; lv[j - 1] = tv;
          int ti = li[j]; li[j] = li[j - 1]; li[j - 1] = ti;
        }
      }
    }
  }
  __shared__ float sv[256 * 16];
  __shared__ int   si[256 * 16];
#pragma unroll
  for (int j = 0; j < 16; ++j) { sv[tid * 16 + j] = lv[j]; si[tid * 16 + j] = li[j]; }
  __syncthreads();
  for (int step = 128; step > 0; step >>= 1) {
    float ov[16]; int oi[16];
    if (tid < step) {
      int ia = 0, ib = 0;
#pragma unroll
      for (int j = 0; j < 16; ++j) {
        bool takeA;
        if (ia >= 16) takeA = false;
        else if (ib >= 16) takeA = true;
        else {
          float av = sv[tid * 16 + ia], bv = sv[(tid + step) * 16 + ib];
          int ai = si[tid * 16 + ia], bi = si[(tid + step) * 16 + ib];
          takeA = (av > bv) || (av == bv && ai < bi);
        }
        if (takeA) { ov[j] = sv[tid * 16 + ia]; oi[j] = si[tid * 16 + ia]; ++ia; }
        else       { ov[j] = sv[(tid + step) * 16 + ib]; oi[j] = si[(tid + step) * 16 + ib]; ++ib; }
      }
    }
    __syncthreads();
    if (tid < step) {
#pragma unroll
      for (int j = 0; j < 16; ++j) { sv[tid * 16 + j] = ov[j]; si[tid * 16 + j] = oi[j]; }
    }
    __syncthreads();
  }
  if (tid < 16) {
    int idx = si[tid];
    float xi = (float)(idx & 127) * 4.0f + 2.0f;   // Wf=128, STRIDE=4
    float yi = (float)(idx >> 7) * 4.0f + 2.0f;
    size_t o = (size_t)bt * 16 + tid;
    p_patch[o * 2 + 0] = xi;
    p_patch[o * 2 + 1] = yi;
    ref[o * 2 + 0] = fminf(fmaxf(xi * (1.0f / 512.0f), 0.f), 1.f);
    ref[o * 2 + 1] = fminf(fmaxf(yi * (1.0f / 384.0f), 0.f), 1.f);
  }
}

// ================= generic tiled fp32 GEMM =================
struct RowDirect {
  const float* A; int K;
  __device__ __forceinline__ const float* row(int r) const { return A + (size_t)r * K; }
};
struct RowVal {  // gathers rows of concat([f4,f8,f16,f32], axis=1), shape (B, 16320, 256)
  const float* f4; const float* f8; const float* f16; const float* f32;
  __device__ __forceinline__ const float* row(int r) const {
    int b = r / CS, s = r - b * CS;
    if (s < 12288) return f4 + ((size_t)b * 12288 + s) * CD;
    if (s < 15360) return f8 + ((size_t)b * 3072 + (s - 12288)) * CD;
    if (s < 16128) return f16 + ((size_t)b * 768 + (s - 15360)) * CD;
    return f32 + ((size_t)b * 192 + (s - 16128)) * CD;
  }
};

// C[M,N] = A[M,K] @ B[K,N] + bias ; M%64==0, N%64==0, K%16==0
template <typename RM, bool RELU>
__global__ __launch_bounds__(256) void gemm_f32(RM rm, const float* __restrict__ Bm,
                                                const float* __restrict__ bias,
                                                float* __restrict__ C, int N, int Kd) {
  __shared__ float As[16][65];
  __shared__ float Bs[16][65];
  const int tid = threadIdx.x;
  const int tx = tid & 15, ty = tid >> 4;
  const int row0 = blockIdx.y * 64, col0 = blockIdx.x * 64;
  const int lr = tid >> 2, lc = (tid & 3) * 4;
  const float* arow = rm.row(row0 + lr) + lc;
  const int brow = tid >> 6, bcol = tid & 63;
  float acc[4][4] = {};
  for (int k0 = 0; k0 < Kd; k0 += 16) {
    float4 a4 = *reinterpret_cast<const float4*>(arow + k0);
    As[lc + 0][lr] = a4.x; As[lc + 1][lr] = a4.y;
    As[lc + 2][lr] = a4.z; As[lc + 3][lr] = a4.w;
#pragma unroll
    for (int i = 0; i < 4; ++i)
      Bs[brow + i * 4][bcol] = Bm[(size_t)(k0 + brow + i * 4) * N + col0 + bcol];
    __syncthreads();
#pragma unroll
    for (int kk = 0; kk < 16; ++kk) {
      float av[4], bv[4];
#pragma unroll
      for (int i = 0; i < 4; ++i) av[i] = As[kk][ty * 4 + i];
#pragma unroll
      for (int j = 0; j < 4; ++j) bv[j] = Bs[kk][tx * 4 + j];
#pragma unroll
      for (int i = 0; i < 4; ++i)
#pragma unroll
        for (int j = 0; j < 4; ++j) acc[i][j] += av[i] * bv[j];
    }
    __syncthreads();
  }
#pragma unroll
  for (int i = 0; i < 4; ++i) {
    int r = row0 + ty * 4 + i;
    float* crow = C + (size_t)r * N + col0 + tx * 4;
    float4 o;
#pragma unroll
    for (int j = 0; j < 4; ++j) {
      float v = acc[i][j] + bias[col0 + tx * 4 + j];
      if (RELU) v = fmaxf(v, 0.f);
      (&o.x)[j] = v;
    }
    *reinterpret_cast<float4*>(crow) = o;
  }
}

// ================= small utility kernels =================
// dst rows (256 floats) = src rows (r>>shift)
__global__ void bcast_rows(const float4* __restrict__ src, float4* __restrict__ dst,
                           int n4, int shift) {
  int i = blockIdx.x * 256 + threadIdx.x;
  if (i >= n4) return;
  int r = i >> 6, j = i & 63;
  dst[i] = src[((size_t)(r >> shift) << 6) + j];
}

// dst rows (512 floats) = [s1 row r (256), s2 row r>>shift (256)]
__global__ void concat_rows(const float4* __restrict__ s1, const float4* __restrict__ s2,
                            float4* __restrict__ dst, int n4, int shift) {
  int i = blockIdx.x * 256 + threadIdx.x;
  if (i >= n4) return;
  int r = i >> 7, j = i & 127;
  dst[i] = (j < 64) ? s1[((size_t)r << 6) + j]
                    : s2[((size_t)(r >> shift) << 6) + (j - 64)];
}

__global__ void softmax16_kernel(float* __restrict__ aw, int n) {
  int g = blockIdx.x * 256 + threadIdx.x;
  if (g >= n) return;
  float* p = aw + (size_t)g * 16;
  float mx = -INFINITY;
  for (int j = 0; j < 16; ++j) mx = fmaxf(mx, p[j]);
  float s = 0.f;
  for (int j = 0; j < 16; ++j) { float e = expf(p[j] - mx); p[j] = e; s += e; }
  float inv = 1.f / s;
  for (int j = 0; j < 16; ++j) p[j] *= inv;
}

// ================= ms-deform sampling =================
__global__ __launch_bounds__(256) void msdeform_kernel(const float* __restrict__ val,
                                                       const float* __restrict__ off,
                                                       const float* __restrict__ aw,
                                                       const float* __restrict__ ref,
                                                       float* __restrict__ attn_pre) {
  const int r = blockIdx.x;       // b*1024 + t*16 + k
  const int b = r >> 10;
  const int tid = threadIdx.x;
  const int h = tid >> 5, c = tid & 31;
  const float rx = ref[(size_t)r * 2], ry = ref[(size_t)r * 2 + 1];
  const float* offr = off + (size_t)r * 256;
  const float* awr = aw + (size_t)r * 128;
  const float* vb = val + (size_t)b * CS * CD;
  float acc = 0.f;
  const int HL[4] = {96, 48, 24, 12}, WL[4] = {128, 64, 32, 16};
  const int ST[4] = {0, 12288, 15360, 16128};
#pragma unroll
  for (int l = 0; l < 4; ++l) {
    const int Hl = HL[l], Wl = WL[l], st = ST[l];
#pragma unroll
    for (int p = 0; p < 4; ++p) {
      int oi = ((h * 4 + l) * 4 + p) * 2;
      float x = rx * (float)Wl + offr[oi] - 0.5f;
      float y = ry * (float)Hl + offr[oi + 1] - 0.5f;
      float w = awr[h * 16 + l * 4 + p];
      float x0f = floorf(x), y0f = floorf(y);
      float lx = x - x0f, ly = y - y0f;
      int x0 = (int)x0f, y0 = (int)y0f;
#pragma unroll
      for (int cy = 0; cy < 2; ++cy)
#pragma unroll
        for (int cx = 0; cx < 2; ++cx) {
          int xi = x0 + cx, yi = y0 + cy;
          if (xi >= 0 && xi < Wl && yi >= 0 && yi < Hl) {
            float wc = (cx ? lx : 1.f - lx) * (cy ? ly : 1.f - ly);
            int rowi = st + yi * Wl + xi;
            acc += w * wc * vb[(size_t)rowi * CD + h * 32 + c];
          }
        }
    }
  }
  attn_pre[(size_t)r * 256 + tid] = acc;
}

// ================= residual + layernorm (D=256, block=256) =================
__global__ __launch_bounds__(256) void resln_kernel(const float* __restrict__ x,
                                                    const float* __restrict__ res,
                                                    const float* __restrict__ g,
                                                    const float* __restrict__ bta,
                                                    float* __restrict__ out) {
  const int r = blockIdx.x, tid = threadIdx.x;
  const size_t off = (size_t)r * 256 + tid;
  float v = x[off] + res[off];
  __shared__ float s1[256], s2[256];
  s1[tid] = v; s2[tid] = v * v;
  __syncthreads();
  for (int st = 128; st > 0; st >>= 1) {
    if (tid < st) { s1[tid] += s1[tid + st]; s2[tid] += s2[tid + st]; }
    __syncthreads();
  }
  float m = s1[0] * (1.f / 256.f);
  float var = s2[0] * (1.f / 256.f) - m * m;
  out[off] = (v - m) * rsqrtf(var + 1e-5f) * g[tid] + bta[tid];
}

// ================= u/s logits (wave per row) =================
__global__ __launch_bounds__(256) void logits_kernel(const float* __restrict__ fused,
                                                     const float* __restrict__ cW, const float* __restrict__ cb,
                                                     const float* __restrict__ sW, const float* __restrict__ sb,
                                                     float* __restrict__ u, float* __restrict__ s) {
  int r = blockIdx.x * 4 + (threadIdx.x >> 6);
  int lane = threadIdx.x & 63;
  const float* row = fused + (size_t)r * 256;
  float su = 0.f, ss = 0.f;
#pragma unroll
  for (int j = 0; j < 4; ++j) {
    float v = row[lane + j * 64];
    su += v * cW[lane + j * 64];
    ss += v * sW[lane + j * 64];
  }
  for (int o = 32; o > 0; o >>= 1) { su += __shfl_down(su, o); ss += __shfl_down(ss, o); }
  if (lane == 0) { u[r] = su + cb[0]; s[r] = ss + sb[0]; }
}

// ================= 16-key attention (block per (b,t)) =================
__global__ __launch_bounds__(256) void attn_kernel(const float* __restrict__ qh,
                                                   const float* __restrict__ kh,
                                                   const float* __restrict__ vh,
                                                   float* __restrict__ o) {
  const int gq = blockIdx.x;     // 0..511
  const int tid = threadIdx.x;
  const int h = tid >> 5, d = tid & 31;
  const float q = qh[(size_t)gq * 256 + h * 32 + d];
  float sc[16];
  float mx = -INFINITY;
#pragma unroll
  for (int k = 0; k < 16; ++k) {
    float s = q * kh[((size_t)gq * 16 + k) * 256 + h * 32 + d];
#pragma unroll
    for (int o2 = 16; o2 > 0; o2 >>= 1) s += __shfl_xor(s, o2);
    s *= 0.17677669529663687f;  // 32^-0.5
    sc[k] = s; mx = fmaxf(mx, s);
  }
  float den = 0.f;
#pragma unroll
  for (int k = 0; k < 16; ++k) { sc[k] = expf(sc[k] - mx); den += sc[k]; }
  float inv = 1.f / den, acc = 0.f;
#pragma unroll
  for (int k = 0; k < 16; ++k)
    acc += sc[k] * vh[((size_t)gq * 16 + k) * 256 + h * 32 + d];
  o[(size_t)gq * 256 + tid] = acc * inv;
}

// ================= workspace layout (floats) =================
constexpr size_t OFF_VAL  = 0;                                   // 8*16320*256
constexpr size_t OFF_QK   = OFF_VAL + (size_t)CB * CS * CD;      // 8192*256
constexpr size_t OFF_TMP  = OFF_QK + (size_t)CBQ * CD;           // 8192*256 (off / gemm-out)
constexpr size_t OFF_AW   = OFF_TMP + (size_t)CBQ * CD;          // 8192*128
constexpr size_t OFF_ATT  = OFF_AW + (size_t)CBQ * 128;          // 8192*256 (attn_pre / fused)
constexpr size_t OFF_HID  = OFF_ATT + (size_t)CBQ * CD;          // 8192*1024 (hid / concat bufs)
constexpr size_t OFF_REF  = OFF_HID + (size_t)CBQ * CDFF;        // 8192*2
constexpr size_t OFF_KH   = OFF_REF + (size_t)CBQ * 2;           // 8192*256
constexpr size_t OFF_VH   = OFF_KH + (size_t)CBQ * CD;           // 8192*256
constexpr size_t OFF_QH   = OFF_VH + (size_t)CBQ * CD;           // 512*256
constexpr size_t OFF_OB   = OFF_QH + 512 * 256;                  // 512*256
constexpr size_t OFF_T3   = OFF_OB + 512 * 256;                  // 512*256
constexpr size_t OFF_O1   = OFF_T3 + 512 * 256;                  // 512*256
constexpr size_t OFF_O2   = OFF_O1 + 512 * 256;                  // 512*256
constexpr size_t OFF_FH   = OFF_O2 + 512 * 256;                  // 512*1024
constexpr size_t WS_NEED  = OFF_FH + 512 * 1024;                 // total floats

extern "C" void kernel_launch(void* const* d_in, const int* in_sizes, int n_in,
                              void* d_out, int out_size, void* d_ws, size_t ws_size,
                              hipStream_t stream) {
  // Safety: if the harness workspace is smaller than our layout, do not launch
  // (clean absmax failure instead of OOB writes / container death).
  if (ws_size < WS_NEED * sizeof(float)) return;

  const float* q_t    = (const float*)d_in[0];
  const float* f4     = (const float*)d_in[1];
  const float* f8     = (const float*)d_in[2];
  const float* f16    = (const float*)d_in[3];
  const float* f32p   = (const float*)d_in[4];
  const float* c_t    = (const float*)d_in[5];
  const float* off_W  = (const float*)d_in[6];
  const float* off_b  = (const float*)d_in[7];
  const float* attw_W = (const float*)d_in[8];
  const float* attw_b = (const float*)d_in[9];
  const float* vW     = (const float*)d_in[10];
  const float* vb     = (const float*)d_in[11];
  const float* oW     = (const float*)d_in[12];
  const float* ob     = (const float*)d_in[13];
  const float* ln1_g  = (const float*)d_in[14];
  const float* ln1_b  = (const float*)d_in[15];
  const float* ffn1_W = (const float*)d_in[16];
  const float* ffn1_b = (const float*)d_in[17];
  const float* ffn2_W = (const float*)d_in[18];
  const float* ffn2_b = (const float*)d_in[19];
  const float* ln2_g  = (const float*)d_in[20];
  const float* ln2_b  = (const float*)d_in[21];
  const float* fq_W   = (const float*)d_in[22];
  const float* fq_b   = (const float*)d_in[23];
  const float* fk_W   = (const float*)d_in[24];
  const float* fk_b   = (const float*)d_in[25];
  const float* fv_W   = (const float*)d_in[26];
  const float* fv_b   = (const float*)d_in[27];
  const float* fo_W   = (const float*)d_in[28];
  const float* fo_b   = (const float*)d_in[29];
  const float* fln1_g = (const float*)d_in[30];
  const float* fln1_b = (const float*)d_in[31];
  const float* fffn1_W= (const float*)d_in[32];
  const float* fffn1_b= (const float*)d_in[33];
  const float* fffn2_W= (const float*)d_in[34];
  const float* fffn2_b= (const float*)d_in[35];
  const float* fln2_g = (const float*)d_in[36];
  const float* fln2_b = (const float*)d_in[37];
  const float* fus_W  = (const float*)d_in[38];
  const float* fus_b  = (const float*)d_in[39];
  const float* fin_W  = (const float*)d_in[40];
  const float* fin_b  = (const float*)d_in[41];
  const float* cert_W = (const float*)d_in[42];
  const float* cert_b = (const float*)d_in[43];
  const float* sc_W   = (const float*)d_in[44];
  const float* sc_b   = (const float*)d_in[45];

  float* ws = (float*)d_ws;
  float* out = (float*)d_out;

  float* val   = ws + OFF_VAL;
  float* qk    = ws + OFF_QK;
  float* tmp   = ws + OFF_TMP;
  float* awb   = ws + OFF_AW;
  float* attp  = ws + OFF_ATT;   // also "fused"
  float* hid   = ws + OFF_HID;   // also concat buffers
  float* ref   = ws + OFF_REF;
  float* kh    = ws + OFF_KH;
  float* vh    = ws + OFF_VH;
  float* qh    = ws + OFF_QH;
  float* obuf  = ws + OFF_OB;
  float* t3    = ws + OFF_T3;
  float* o1    = ws + OFF_O1;
  float* o2    = ws + OFF_O2;
  float* fhid  = ws + OFF_FH;

  float* out_main = out;               // 512*256
  float* out_pp   = out + 131072;      // (B,NT,K,2)
  float* out_u    = out + 147456;      // (B,NT,K)
  float* out_s    = out + 155648;

  // 1) top-k -> p_patch, ref
  topk_kernel<<<CB * CNT, 256, 0, stream>>>(c_t, out_pp, ref);

  // 2) qk init: broadcast q_t rows 16x
  {
    int n4 = CBQ * 64;
    bcast_rows<<<(n4 + 255) / 256, 256, 0, stream>>>((const float4*)q_t, (float4*)qk, n4, 4);
  }

  // 3) refinement layers
  for (int l = 0; l < 3; ++l) {
    // val = f_scales @ vW[l] + vb[l]   (130560 x 256)
    gemm_f32<RowVal, false><<<dim3(CD / 64, (CB * CS) / 64), 256, 0, stream>>>(
        RowVal{f4, f8, f16, f32p}, vW + (size_t)l * CD * CD, vb + l * CD, val, CD, CD);
    // off = qk @ off_W[l] + off_b[l]
    gemm_f32<RowDirect, false><<<dim3(CD / 64, CBQ / 64), 256, 0, stream>>>(
        RowDirect{qk, CD}, off_W + (size_t)l * CD * 256, off_b + l * 256, tmp, 256, CD);
    // aw logits = qk @ attw_W[l] + attw_b[l]
    gemm_f32<RowDirect, false><<<dim3(128 / 64, CBQ / 64), 256, 0, stream>>>(
        RowDirect{qk, CD}, attw_W + (size_t)l * CD * 128, attw_b + l * 128, awb, 128, CD);
    // softmax over 16 per (q, head)
    softmax16_kernel<<<(CBQ * CNH + 255) / 256, 256, 0, stream>>>(awb, CBQ * CNH);
    // sampling
    msdeform_kernel<<<CBQ, 256, 0, stream>>>(val, tmp, awb, ref, attp);
    // o-proj
    gemm_f32<RowDirect, false><<<dim3(CD / 64, CBQ / 64), 256, 0, stream>>>(
        RowDirect{attp, CD}, oW + (size_t)l * CD * CD, ob + l * CD, tmp, CD, CD);
    // qk = LN(qk + attn)
    resln_kernel<<<CBQ, 256, 0, stream>>>(tmp, qk, ln1_g + l * CD, ln1_b + l * CD, qk);
    // ffn
    gemm_f32<RowDirect, true><<<dim3(CDFF / 64, CBQ / 64), 256, 0, stream>>>(
        RowDirect{qk, CD}, ffn1_W + (size_t)l * CD * CDFF, ffn1_b + l * CDFF, hid, CDFF, CD);
    gemm_f32<RowDirect, false><<<dim3(CD / 64, CBQ / 64), 256, 0, stream>>>(
        RowDirect{hid, CDFF}, ffn2_W + (size_t)l * CDFF * CD, ffn2_b + l * CD, tmp, CD, CDFF);
    resln_kernel<<<CBQ, 256, 0, stream>>>(tmp, qk, ln2_g + l * CD, ln2_b + l * CD, qk);
  }

  // 4) fusion: cat([qk, q_bcast]) @ fus_W + fus_b
  {
    int n4 = CBQ * 128;
    concat_rows<<<(n4 + 255) / 256, 256, 0, stream>>>((const float4*)qk, (const float4*)q_t,
                                                      (float4*)hid, n4, 4);
  }
  gemm_f32<RowDirect, false><<<dim3(CD / 64, CBQ / 64), 256, 0, stream>>>(
      RowDirect{hid, 512}, fus_W, fus_b, attp, CD, 512);  // attp = fused

  // 5) u/s logits
  logits_kernel<<<CBQ / 4, 256, 0, stream>>>(attp, cert_W, cert_b, sc_W, sc_b, out_u, out_s);

  // 6) single-query attention over K=16
  gemm_f32<RowDirect, false><<<dim3(CD / 64, 512 / 64), 256, 0, stream>>>(
      RowDirect{q_t, CD}, fq_W, fq_b, qh, CD, CD);
  gemm_f32<RowDirect, false><<<dim3(CD / 64, CBQ / 64), 256, 0, stream>>>(
      RowDirect{attp, CD}, fk_W, fk_b, kh, CD, CD);
  gemm_f32<RowDirect, false><<<dim3(CD / 64, CBQ / 64), 256, 0, stream>>>(
      RowDirect{attp, CD}, fv_W, fv_b, vh, CD, CD);
  attn_kernel<<<512, 256, 0, stream>>>(qh, kh, vh, obuf);

  // 7) o = LN(qf + o@fo_W + fo_b)
  gemm_f32<RowDirect, false><<<dim3(CD / 64, 512 / 64), 256, 0, stream>>>(
      RowDirect{obuf, CD}, fo_W, fo_b, t3, CD, CD);
  resln_kernel<<<512, 256, 0, stream>>>(t3, q_t, fln1_g, fln1_b, o1);

  // 8) final FFN + LN
  gemm_f32<RowDirect, true><<<dim3(CDFF / 64, 512 / 64), 256, 0, stream>>>(
      RowDirect{o1, CD}, fffn1_W, fffn1_b, fhid, CDFF, CD);
  gemm_f32<RowDirect, false><<<dim3(CD / 64, 512 / 64), 256, 0, stream>>>(
      RowDirect{fhid, CDFF}, fffn2_W, fffn2_b, t3, CD, CDFF);
  resln_kernel<<<512, 256, 0, stream>>>(t3, o1, fln2_g, fln2_b, o2);

  // 9) out = cat([o2, qf]) @ fin_W + fin_b
  {
    int n4 = 512 * 128;
    concat_rows<<<(n4 + 255) / 256, 256, 0, stream>>>((const float4*)o2, (const float4*)q_t,
                                                      (float4*)hid, n4, 0);
  }
  gemm_f32<RowDirect, false><<<dim3(CD / 64, 512 / 64), 256, 0, stream>>>(
      RowDirect{hid, 512}, fin_W, fin_b, out_main, CD, 512);
}

// Round 8
// 1426.333 us; speedup vs baseline: 2.1655x; 2.1655x over previous
//
#include <hip/hip_runtime.h>
#include <math.h>

// ---- problem constants ----
constexpr int CB = 8, CNT = 64, CD = 256, CKSEL = 16;
constexpr int CNH = 8, CNL = 4, CNP = 4, CDH = 32;
constexpr int CP = 12288, CS = 16320, CQ = 1024, CBQ = 8192, CDFF = 1024;

using short8 = __attribute__((ext_vector_type(8))) short;
using f32x4  = __attribute__((ext_vector_type(4))) float;

__device__ __forceinline__ ushort f2bf(float f) {  // fp32 -> bf16 RNE
  unsigned u = __float_as_uint(f);
  u += 0x7fff + ((u >> 16) & 1);
  return (ushort)(u >> 16);
}

// ================= top-k =================
__global__ __launch_bounds__(256) void topk_kernel(const float* __restrict__ c_t,
                                                   float* __restrict__ p_patch,
                                                   float* __restrict__ ref) {
  const int bt = blockIdx.x;  // b*64 + t
  const float* row = c_t + (size_t)bt * CP;
  const int tid = threadIdx.x;
  float lv[16]; int li[16];
#pragma unroll
  for (int j = 0; j < 16; ++j) { lv[j] = -INFINITY; li[j] = 0x7fffffff; }
  for (int s = tid; s < CP; s += 256) {
    float v = row[s];
    if (v > lv[15]) {       // tie keeps earlier (lower) index: strict >
      lv[15] = v; li[15] = s;
#pragma unroll
      for (int j = 15; j > 0; --j) {
        if (lv[j] > lv[j - 1]) {
          float tv = lv[j]; lv[j] = lv[j - 1]; lv[j - 1] = tv;
          int ti = li[j]; li[j] = li[j - 1]; li[j - 1] = ti;
        }
      }
    }
  }
  __shared__ float sv[256 * 16];
  __shared__ int   si[256 * 16];
#pragma unroll
  for (int j = 0; j < 16; ++j) { sv[tid * 16 + j] = lv[j]; si[tid * 16 + j] = li[j]; }
  __syncthreads();
  for (int step = 128; step > 0; step >>= 1) {
    float ov[16]; int oi[16];
    if (tid < step) {
      int ia = 0, ib = 0;
#pragma unroll
      for (int j = 0; j < 16; ++j) {
        bool takeA;
        if (ia >= 16) takeA = false;
        else if (ib >= 16) takeA = true;
        else {
          float av = sv[tid * 16 + ia], bv = sv[(tid + step) * 16 + ib];
          int ai = si[tid * 16 + ia], bi = si[(tid + step) * 16 + ib];
          takeA = (av > bv) || (av == bv && ai < bi);
        }
        if (takeA) { ov[j] = sv[tid * 16 + ia]; oi[j] = si[tid * 16 + ia]; ++ia; }
        else       { ov[j] = sv[(tid + step) * 16 + ib]; oi[j] = si[(tid + step) * 16 + ib]; ++ib; }
      }
    }
    __syncthreads();
    if (tid < step) {
#pragma unroll
      for (int j = 0; j < 16; ++j) { sv[tid * 16 + j] = ov[j]; si[tid * 16 + j] = oi[j]; }
    }
    __syncthreads();
  }
  if (tid < 16) {
    int idx = si[tid];
    float xi = (float)(idx & 127) * 4.0f + 2.0f;   // Wf=128, STRIDE=4
    float yi = (float)(idx >> 7) * 4.0f + 2.0f;
    size_t o = (size_t)bt * 16 + tid;
    p_patch[o * 2 + 0] = xi;
    p_patch[o * 2 + 1] = yi;
    ref[o * 2 + 0] = fminf(fmaxf(xi * (1.0f / 512.0f), 0.f), 1.f);
    ref[o * 2 + 1] = fminf(fmaxf(yi * (1.0f / 384.0f), 0.f), 1.f);
  }
}

// ================= weight transpose + bf16 convert =================
// src (K x N fp32) -> dst (N x K bf16); K,N multiples of 32; blockIdx.z batches.
__global__ __launch_bounds__(256) void transpose_cvt(const float* __restrict__ src,
                                                     ushort* __restrict__ dst,
                                                     int K, int N,
                                                     size_t sStride, size_t dStride) {
  src += blockIdx.z * sStride;
  dst += blockIdx.z * dStride;
  __shared__ float t[32][33];
  const int n0 = blockIdx.x * 32, k0 = blockIdx.y * 32;
  const int c = threadIdx.x & 31, r = threadIdx.x >> 5;  // r 0..7
#pragma unroll
  for (int i = 0; i < 4; ++i)
    t[r + i * 8][c] = src[(size_t)(k0 + r + i * 8) * N + n0 + c];
  __syncthreads();
#pragma unroll
  for (int i = 0; i < 4; ++i)
    dst[(size_t)(n0 + r + i * 8) * K + k0 + c] = f2bf(t[c][r + i * 8]);
}

// ================= MFMA bf16 GEMM =================
// C[M,N] = A[M,K](fp32) @ B[K,N] + bias, with Bt = B^T pre-converted bf16 (N x K).
// BM=BN=128, BK=32, 256 threads (4 waves, each 64x64).
// M%128==0, N%128==0, K%32==0.
struct RowDirect {
  const float* A; int K;
  __device__ __forceinline__ const float* row(int r) const { return A + (size_t)r * K; }
};
struct RowVal {  // rows of concat([f4,f8,f16,f32], axis=1): (B, 16320, 256)
  const float* f4; const float* f8; const float* f16; const float* f32;
  __device__ __forceinline__ const float* row(int r) const {
    int b = r / CS, s = r - b * CS;
    if (s < 12288) return f4 + ((size_t)b * 12288 + s) * CD;
    if (s < 15360) return f8 + ((size_t)b * 3072 + (s - 12288)) * CD;
    if (s < 16128) return f16 + ((size_t)b * 768 + (s - 15360)) * CD;
    return f32 + ((size_t)b * 192 + (s - 16128)) * CD;
  }
};

__device__ __forceinline__ short8 ldfrag(const ushort* p) {  // 8 contiguous bf16
  ushort4 lo = *(const ushort4*)p;
  ushort4 hi = *(const ushort4*)(p + 4);
  short8 f;
  f[0] = (short)lo.x; f[1] = (short)lo.y; f[2] = (short)lo.z; f[3] = (short)lo.w;
  f[4] = (short)hi.x; f[5] = (short)hi.y; f[6] = (short)hi.z; f[7] = (short)hi.w;
  return f;
}

template <typename RM, bool RELU>
__global__ __launch_bounds__(256) void gemm_bf16(RM rm, const ushort* __restrict__ Bt,
                                                 const float* __restrict__ bias,
                                                 float* __restrict__ C, int N, int K) {
  __shared__ ushort As[128][40];   // +8 pad: 80B row stride (8B aligned, 2-way-ish banks)
  __shared__ ushort Bs[128][40];
  const int tid = threadIdx.x;
  const int lane = tid & 63;
  const int wave = tid >> 6;
  const int wm = (wave >> 1) * 64;   // wave row offset in tile
  const int wn = (wave & 1) * 64;    // wave col offset
  const int row0 = blockIdx.y * 128, col0 = blockIdx.x * 128;

  // staging assignment: each thread owns 16 elements of A-tile and B-tile
  const int sr = tid >> 1;           // 0..127
  const int sk = (tid & 1) * 16;     // 0 or 16
  const float*  arow = rm.row(row0 + sr) + sk;
  const ushort* brow = Bt + (size_t)(col0 + sr) * K + sk;

  const int fr = lane & 15;          // fragment row (within 16)
  const int fk = (lane >> 4) * 8;    // fragment k-offset

  f32x4 acc[4][4] = {};
  for (int k0 = 0; k0 < K; k0 += 32) {
    // stage A: fp32 -> bf16
    float4 a0 = *(const float4*)(arow + k0);
    float4 a1 = *(const float4*)(arow + k0 + 4);
    float4 a2 = *(const float4*)(arow + k0 + 8);
    float4 a3 = *(const float4*)(arow + k0 + 12);
    ushort4 ua0 = {f2bf(a0.x), f2bf(a0.y), f2bf(a0.z), f2bf(a0.w)};
    ushort4 ua1 = {f2bf(a1.x), f2bf(a1.y), f2bf(a1.z), f2bf(a1.w)};
    ushort4 ua2 = {f2bf(a2.x), f2bf(a2.y), f2bf(a2.z), f2bf(a2.w)};
    ushort4 ua3 = {f2bf(a3.x), f2bf(a3.y), f2bf(a3.z), f2bf(a3.w)};
    *(ushort4*)&As[sr][sk + 0]  = ua0;
    *(ushort4*)&As[sr][sk + 4]  = ua1;
    *(ushort4*)&As[sr][sk + 8]  = ua2;
    *(ushort4*)&As[sr][sk + 12] = ua3;
    // stage B: already bf16, N x K row-major
    ushort4 ub0 = *(const ushort4*)(brow + k0);
    ushort4 ub1 = *(const ushort4*)(brow + k0 + 4);
    ushort4 ub2 = *(const ushort4*)(brow + k0 + 8);
    ushort4 ub3 = *(const ushort4*)(brow + k0 + 12);
    *(ushort4*)&Bs[sr][sk + 0]  = ub0;
    *(ushort4*)&Bs[sr][sk + 4]  = ub1;
    *(ushort4*)&Bs[sr][sk + 8]  = ub2;
    *(ushort4*)&Bs[sr][sk + 12] = ub3;
    __syncthreads();

    short8 af[4], bfr[4];
#pragma unroll
    for (int i = 0; i < 4; ++i) {
      af[i]  = ldfrag(&As[wm + i * 16 + fr][fk]);
      bfr[i] = ldfrag(&Bs[wn + i * 16 + fr][fk]);
    }
#pragma unroll
    for (int i = 0; i < 4; ++i)
#pragma unroll
      for (int j = 0; j < 4; ++j)
        acc[i][j] = __builtin_amdgcn_mfma_f32_16x16x32_bf16(af[i], bfr[j], acc[i][j], 0, 0, 0);
    __syncthreads();
  }
  // epilogue: D col = lane&15, row = (lane>>4)*4 + reg   [m89-verified]
  const int orow = row0 + wm + (lane >> 4) * 4;
  const int ocol = col0 + wn + fr;
#pragma unroll
  for (int i = 0; i < 4; ++i)
#pragma unroll
    for (int j = 0; j < 4; ++j) {
      const int cc = ocol + j * 16;
      const float bv = bias[cc];
#pragma unroll
      for (int r = 0; r < 4; ++r) {
        float v = acc[i][j][r] + bv;
        if (RELU) v = fmaxf(v, 0.f);
        C[(size_t)(orow + i * 16 + r) * N + cc] = v;
      }
    }
}

// ================= small utility kernels =================
__global__ void bcast_rows(const float4* __restrict__ src, float4* __restrict__ dst,
                           int n4, int shift) {
  int i = blockIdx.x * 256 + threadIdx.x;
  if (i >= n4) return;
  int r = i >> 6, j = i & 63;
  dst[i] = src[((size_t)(r >> shift) << 6) + j];
}

__global__ void concat_rows(const float4* __restrict__ s1, const float4* __restrict__ s2,
                            float4* __restrict__ dst, int n4, int shift) {
  int i = blockIdx.x * 256 + threadIdx.x;
  if (i >= n4) return;
  int r = i >> 7, j = i & 127;
  dst[i] = (j < 64) ? s1[((size_t)r << 6) + j]
                    : s2[((size_t)(r >> shift) << 6) + (j - 64)];
}

__global__ void softmax16_kernel(float* __restrict__ aw, int n) {
  int g = blockIdx.x * 256 + threadIdx.x;
  if (g >= n) return;
  float* p = aw + (size_t)g * 16;
  float mx = -INFINITY;
  for (int j = 0; j < 16; ++j) mx = fmaxf(mx, p[j]);
  float s = 0.f;
  for (int j = 0; j < 16; ++j) { float e = expf(p[j] - mx); p[j] = e; s += e; }
  float inv = 1.f / s;
  for (int j = 0; j < 16; ++j) p[j] *= inv;
}

// ================= ms-deform sampling =================
__global__ __launch_bounds__(256) void msdeform_kernel(const float* __restrict__ val,
                                                       const float* __restrict__ off,
                                                       const float* __restrict__ aw,
                                                       const float* __restrict__ ref,
                                                       float* __restrict__ attn_pre) {
  const int r = blockIdx.x;       // b*1024 + t*16 + k
  const int b = r >> 10;
  const int tid = threadIdx.x;
  const int h = tid >> 5, c = tid & 31;
  const float rx = ref[(size_t)r * 2], ry = ref[(size_t)r * 2 + 1];
  const float* offr = off + (size_t)r * 256;
  const float* awr = aw + (size_t)r * 128;
  const float* vb = val + (size_t)b * CS * CD;
  float acc = 0.f;
  const int HL[4] = {96, 48, 24, 12}, WL[4] = {128, 64, 32, 16};
  const int ST[4] = {0, 12288, 15360, 16128};
#pragma unroll
  for (int l = 0; l < 4; ++l) {
    const int Hl = HL[l], Wl = WL[l], st = ST[l];
#pragma unroll
    for (int p = 0; p < 4; ++p) {
      int oi = ((h * 4 + l) * 4 + p) * 2;
      float x = rx * (float)Wl + offr[oi] - 0.5f;
      float y = ry * (float)Hl + offr[oi + 1] - 0.5f;
      float w = awr[h * 16 + l * 4 + p];
      float x0f = floorf(x), y0f = floorf(y);
      float lx = x - x0f, ly = y - y0f;
      int x0 = (int)x0f, y0 = (int)y0f;
#pragma unroll
      for (int cy = 0; cy < 2; ++cy)
#pragma unroll
        for (int cx = 0; cx < 2; ++cx) {
          int xi = x0 + cx, yi = y0 + cy;
          if (xi >= 0 && xi < Wl && yi >= 0 && yi < Hl) {
            float wc = (cx ? lx : 1.f - lx) * (cy ? ly : 1.f - ly);
            int rowi = st + yi * Wl + xi;
            acc += w * wc * vb[(size_t)rowi * CD + h * 32 + c];
          }
        }
    }
  }
  attn_pre[(size_t)r * 256 + tid] = acc;
}

// ================= residual + layernorm =================
__global__ __launch_bounds__(256) void resln_kernel(const float* __restrict__ x,
                                                    const float* __restrict__ res,
                                                    const float* __restrict__ g,
                                                    const float* __restrict__ bta,
                                                    float* __restrict__ out) {
  const int r = blockIdx.x, tid = threadIdx.x;
  const size_t off = (size_t)r * 256 + tid;
  float v = x[off] + res[off];
  __shared__ float s1[256], s2[256];
  s1[tid] = v; s2[tid] = v * v;
  __syncthreads();
  for (int st = 128; st > 0; st >>= 1) {
    if (tid < st) { s1[tid] += s1[tid + st]; s2[tid] += s2[tid + st]; }
    __syncthreads();
  }
  float m = s1[0] * (1.f / 256.f);
  float var = s2[0] * (1.f / 256.f) - m * m;
  out[off] = (v - m) * rsqrtf(var + 1e-5f) * g[tid] + bta[tid];
}

// ================= u/s logits =================
__global__ __launch_bounds__(256) void logits_kernel(const float* __restrict__ fused,
                                                     const float* __restrict__ cW, const float* __restrict__ cb,
                                                     const float* __restrict__ sW, const float* __restrict__ sb,
                                                     float* __restrict__ u, float* __restrict__ s) {
  int r = blockIdx.x * 4 + (threadIdx.x >> 6);
  int lane = threadIdx.x & 63;
  const float* row = fused + (size_t)r * 256;
  float su = 0.f, ss = 0.f;
#pragma unroll
  for (int j = 0; j < 4; ++j) {
    float v = row[lane + j * 64];
    su += v * cW[lane + j * 64];
    ss += v * sW[lane + j * 64];
  }
  for (int o = 32; o > 0; o >>= 1) { su += __shfl_down(su, o); ss += __shfl_down(ss, o); }
  if (lane == 0) { u[r] = su + cb[0]; s[r] = ss + sb[0]; }
}

// ================= 16-key attention =================
__global__ __launch_bounds__(256) void attn_kernel(const float* __restrict__ qh,
                                                   const float* __restrict__ kh,
                                                   const float* __restrict__ vh,
                                                   float* __restrict__ o) {
  const int gq = blockIdx.x;     // 0..511
  const int tid = threadIdx.x;
  const int h = tid >> 5, d = tid & 31;
  const float q = qh[(size_t)gq * 256 + h * 32 + d];
  float sc[16];
  float mx = -INFINITY;
#pragma unroll
  for (int k = 0; k < 16; ++k) {
    float s = q * kh[((size_t)gq * 16 + k) * 256 + h * 32 + d];
#pragma unroll
    for (int o2 = 16; o2 > 0; o2 >>= 1) s += __shfl_xor(s, o2);
    s *= 0.17677669529663687f;  // 32^-0.5
    sc[k] = s; mx = fmaxf(mx, s);
  }
  float den = 0.f;
#pragma unroll
  for (int k = 0; k < 16; ++k) { sc[k] = expf(sc[k] - mx); den += sc[k]; }
  float inv = 1.f / den, acc = 0.f;
#pragma unroll
  for (int k = 0; k < 16; ++k)
    acc += sc[k] * vh[((size_t)gq * 16 + k) * 256 + h * 32 + d];
  o[(size_t)gq * 256 + tid] = acc * inv;
}

// ================= workspace layout (floats) =================
constexpr size_t OFF_VAL  = 0;                                   // 8*16320*256
constexpr size_t OFF_QK   = OFF_VAL + (size_t)CB * CS * CD;
constexpr size_t OFF_TMP  = OFF_QK + (size_t)CBQ * CD;
constexpr size_t OFF_AW   = OFF_TMP + (size_t)CBQ * CD;
constexpr size_t OFF_ATT  = OFF_AW + (size_t)CBQ * 128;
constexpr size_t OFF_HID  = OFF_ATT + (size_t)CBQ * CD;
constexpr size_t OFF_REF  = OFF_HID + (size_t)CBQ * CDFF;
constexpr size_t OFF_KH   = OFF_REF + (size_t)CBQ * 2;
constexpr size_t OFF_VH   = OFF_KH + (size_t)CBQ * CD;
constexpr size_t OFF_QH   = OFF_VH + (size_t)CBQ * CD;
constexpr size_t OFF_OB   = OFF_QH + 512 * 256;
constexpr size_t OFF_T3   = OFF_OB + 512 * 256;
constexpr size_t OFF_O1   = OFF_T3 + 512 * 256;
constexpr size_t OFF_O2   = OFF_O1 + 512 * 256;
constexpr size_t OFF_FH   = OFF_O2 + 512 * 256;
constexpr size_t OFF_WT   = OFF_FH + 512 * 1024;                 // bf16 weight region

// bf16 weight sub-offsets (ushort units within the WT region)
constexpr size_t WT_vW    = 0;              // 3 x 256x256
constexpr size_t WT_off   = 196608;         // 3 x 256x256
constexpr size_t WT_attw  = 393216;         // 3 x 128x256
constexpr size_t WT_oW    = 491520;         // 3 x 256x256
constexpr size_t WT_ffn1  = 688128;         // 3 x 1024x256
constexpr size_t WT_ffn2  = 1474560;        // 3 x 256x1024
constexpr size_t WT_fus   = 2260992;        // 256x512
constexpr size_t WT_fq    = 2392064;        // 256x256
constexpr size_t WT_fk    = 2457600;
constexpr size_t WT_fv    = 2523136;
constexpr size_t WT_fo    = 2588672;
constexpr size_t WT_fffn1 = 2654208;        // 1024x256
constexpr size_t WT_fffn2 = 2916352;        // 256x1024
constexpr size_t WT_fin   = 3178496;        // 256x512
constexpr size_t WT_TOTAL = 3309568;        // ushorts
constexpr size_t WS_NEED  = OFF_WT + (WT_TOTAL + 1) / 2;         // floats

extern "C" void kernel_launch(void* const* d_in, const int* in_sizes, int n_in,
                              void* d_out, int out_size, void* d_ws, size_t ws_size,
                              hipStream_t stream) {
  if (ws_size < WS_NEED * sizeof(float)) return;  // clean fail instead of OOB

  const float* q_t    = (const float*)d_in[0];
  const float* f4     = (const float*)d_in[1];
  const float* f8     = (const float*)d_in[2];
  const float* f16    = (const float*)d_in[3];
  const float* f32p   = (const float*)d_in[4];
  const float* c_t    = (const float*)d_in[5];
  const float* off_W  = (const float*)d_in[6];
  const float* off_b  = (const float*)d_in[7];
  const float* attw_W = (const float*)d_in[8];
  const float* attw_b = (const float*)d_in[9];
  const float* vW     = (const float*)d_in[10];
  const float* vb     = (const float*)d_in[11];
  const float* oW     = (const float*)d_in[12];
  const float* ob     = (const float*)d_in[13];
  const float* ln1_g  = (const float*)d_in[14];
  const float* ln1_b  = (const float*)d_in[15];
  const float* ffn1_W = (const float*)d_in[16];
  const float* ffn1_b = (const float*)d_in[17];
  const float* ffn2_W = (const float*)d_in[18];
  const float* ffn2_b = (const float*)d_in[19];
  const float* ln2_g  = (const float*)d_in[20];
  const float* ln2_b  = (const float*)d_in[21];
  const float* fq_W   = (const float*)d_in[22];
  const float* fq_b   = (const float*)d_in[23];
  const float* fk_W   = (const float*)d_in[24];
  const float* fk_b   = (const float*)d_in[25];
  const float* fv_W   = (const float*)d_in[26];
  const float* fv_b   = (const float*)d_in[27];
  const float* fo_W   = (const float*)d_in[28];
  const float* fo_b   = (const float*)d_in[29];
  const float* fln1_g = (const float*)d_in[30];
  const float* fln1_b = (const float*)d_in[31];
  const float* fffn1_W= (const float*)d_in[32];
  const float* fffn1_b= (const float*)d_in[33];
  const float* fffn2_W= (const float*)d_in[34];
  const float* fffn2_b= (const float*)d_in[35];
  const float* fln2_g = (const float*)d_in[36];
  const float* fln2_b = (const float*)d_in[37];
  const float* fus_W  = (const float*)d_in[38];
  const float* fus_b  = (const float*)d_in[39];
  const float* fin_W  = (const float*)d_in[40];
  const float* fin_b  = (const float*)d_in[41];
  const float* cert_W = (const float*)d_in[42];
  const float* cert_b = (const float*)d_in[43];
  const float* sc_W   = (const float*)d_in[44];
  const float* sc_b   = (const float*)d_in[45];

  float* ws = (float*)d_ws;
  float* out = (float*)d_out;

  float* val   = ws + OFF_VAL;
  float* qk    = ws + OFF_QK;
  float* tmp   = ws + OFF_TMP;
  float* awb   = ws + OFF_AW;
  float* attp  = ws + OFF_ATT;   // also "fused"
  float* hid   = ws + OFF_HID;   // also concat buffers
  float* ref   = ws + OFF_REF;
  float* kh    = ws + OFF_KH;
  float* vh    = ws + OFF_VH;
  float* qh    = ws + OFF_QH;
  float* obuf  = ws + OFF_OB;
  float* t3    = ws + OFF_T3;
  float* o1    = ws + OFF_O1;
  float* o2    = ws + OFF_O2;
  float* fhid  = ws + OFF_FH;
  ushort* wt   = (ushort*)(ws + OFF_WT);

  float* out_main = out;               // 512*256
  float* out_pp   = out + 131072;      // (B,NT,K,2)
  float* out_u    = out + 147456;      // (B,NT,K)
  float* out_s    = out + 155648;

  // 0) weight transpose+convert pre-pass (bf16 N x K)
  {
    auto T = [&](const float* src, size_t wtOff, int K_, int N_, int cnt, size_t sStr, size_t dStr) {
      transpose_cvt<<<dim3(N_ / 32, K_ / 32, cnt), 256, 0, stream>>>(src, wt + wtOff, K_, N_, sStr, dStr);
    };
    T(vW,      WT_vW,    256, 256,  3, 65536, 65536);
    T(off_W,   WT_off,   256, 256,  3, 65536, 65536);
    T(attw_W,  WT_attw,  256, 128,  3, 32768, 32768);
    T(oW,      WT_oW,    256, 256,  3, 65536, 65536);
    T(ffn1_W,  WT_ffn1,  256, 1024, 3, 262144, 262144);
    T(ffn2_W,  WT_ffn2,  1024, 256, 3, 262144, 262144);
    T(fus_W,   WT_fus,   512, 256,  1, 0, 0);
    T(fq_W,    WT_fq,    256, 256,  1, 0, 0);
    T(fk_W,    WT_fk,    256, 256,  1, 0, 0);
    T(fv_W,    WT_fv,    256, 256,  1, 0, 0);
    T(fo_W,    WT_fo,    256, 256,  1, 0, 0);
    T(fffn1_W, WT_fffn1, 256, 1024, 1, 0, 0);
    T(fffn2_W, WT_fffn2, 1024, 256, 1, 0, 0);
    T(fin_W,   WT_fin,   512, 256,  1, 0, 0);
  }

  // 1) top-k -> p_patch, ref
  topk_kernel<<<CB * CNT, 256, 0, stream>>>(c_t, out_pp, ref);

  // 2) qk init: broadcast q_t rows 16x
  {
    int n4 = CBQ * 64;
    bcast_rows<<<(n4 + 255) / 256, 256, 0, stream>>>((const float4*)q_t, (float4*)qk, n4, 4);
  }

  // 3) refinement layers
  for (int l = 0; l < 3; ++l) {
    // val = f_scales @ vW[l] + vb[l]   (130560 x 256, K=256)
    gemm_bf16<RowVal, false><<<dim3(2, 1020), 256, 0, stream>>>(
        RowVal{f4, f8, f16, f32p}, wt + WT_vW + (size_t)l * 65536, vb + l * CD, val, 256, 256);
    // off = qk @ off_W[l] + off_b[l]   (8192 x 256)
    gemm_bf16<RowDirect, false><<<dim3(2, 64), 256, 0, stream>>>(
        RowDirect{qk, CD}, wt + WT_off + (size_t)l * 65536, off_b + l * 256, tmp, 256, 256);
    // aw logits = qk @ attw_W[l] + attw_b[l]   (8192 x 128)
    gemm_bf16<RowDirect, false><<<dim3(1, 64), 256, 0, stream>>>(
        RowDirect{qk, CD}, wt + WT_attw + (size_t)l * 32768, attw_b + l * 128, awb, 128, 256);
    softmax16_kernel<<<(CBQ * CNH + 255) / 256, 256, 0, stream>>>(awb, CBQ * CNH);
    msdeform_kernel<<<CBQ, 256, 0, stream>>>(val, tmp, awb, ref, attp);
    // o-proj   (8192 x 256)
    gemm_bf16<RowDirect, false><<<dim3(2, 64), 256, 0, stream>>>(
        RowDirect{attp, CD}, wt + WT_oW + (size_t)l * 65536, ob + l * CD, tmp, 256, 256);
    resln_kernel<<<CBQ, 256, 0, stream>>>(tmp, qk, ln1_g + l * CD, ln1_b + l * CD, qk);
    // ffn1 (8192 x 1024, relu), ffn2 (8192 x 256, K=1024)
    gemm_bf16<RowDirect, true><<<dim3(8, 64), 256, 0, stream>>>(
        RowDirect{qk, CD}, wt + WT_ffn1 + (size_t)l * 262144, ffn1_b + l * CDFF, hid, 1024, 256);
    gemm_bf16<RowDirect, false><<<dim3(2, 64), 256, 0, stream>>>(
        RowDirect{hid, CDFF}, wt + WT_ffn2 + (size_t)l * 262144, ffn2_b + l * CD, tmp, 256, 1024);
    resln_kernel<<<CBQ, 256, 0, stream>>>(tmp, qk, ln2_g + l * CD, ln2_b + l * CD, qk);
  }

  // 4) fusion: cat([qk, q_bcast]) @ fus_W + fus_b
  {
    int n4 = CBQ * 128;
    concat_rows<<<(n4 + 255) / 256, 256, 0, stream>>>((const float4*)qk, (const float4*)q_t,
                                                      (float4*)hid, n4, 4);
  }
  gemm_bf16<RowDirect, false><<<dim3(2, 64), 256, 0, stream>>>(
      RowDirect{hid, 512}, wt + WT_fus, fus_b, attp, 256, 512);  // attp = fused

  // 5) u/s logits
  logits_kernel<<<CBQ / 4, 256, 0, stream>>>(attp, cert_W, cert_b, sc_W, sc_b, out_u, out_s);

  // 6) single-query attention over K=16
  gemm_bf16<RowDirect, false><<<dim3(2, 4), 256, 0, stream>>>(
      RowDirect{q_t, CD}, wt + WT_fq, fq_b, qh, 256, 256);
  gemm_bf16<RowDirect, false><<<dim3(2, 64), 256, 0, stream>>>(
      RowDirect{attp, CD}, wt + WT_fk, fk_b, kh, 256, 256);
  gemm_bf16<RowDirect, false><<<dim3(2, 64), 256, 0, stream>>>(
      RowDirect{attp, CD}, wt + WT_fv, fv_b, vh, 256, 256);
  attn_kernel<<<512, 256, 0, stream>>>(qh, kh, vh, obuf);

  // 7) o = LN(qf + o@fo_W + fo_b)
  gemm_bf16<RowDirect, false><<<dim3(2, 4), 256, 0, stream>>>(
      RowDirect{obuf, CD}, wt + WT_fo, fo_b, t3, 256, 256);
  resln_kernel<<<512, 256, 0, stream>>>(t3, q_t, fln1_g, fln1_b, o1);

  // 8) final FFN + LN
  gemm_bf16<RowDirect, true><<<dim3(8, 4), 256, 0, stream>>>(
      RowDirect{o1, CD}, wt + WT_fffn1, fffn1_b, fhid, 1024, 256);
  gemm_bf16<RowDirect, false><<<dim3(2, 4), 256, 0, stream>>>(
      RowDirect{fhid, CDFF}, wt + WT_fffn2, fffn2_b, t3, 256, 1024);
  resln_kernel<<<512, 256, 0, stream>>>(t3, o1, fln2_g, fln2_b, o2);

  // 9) out = cat([o2, qf]) @ fin_W + fin_b
  {
    int n4 = 512 * 128;
    concat_rows<<<(n4 + 255) / 256, 256, 0, stream>>>((const float4*)o2, (const float4*)q_t,
                                                      (float4*)hid, n4, 0);
  }
  gemm_bf16<RowDirect, false><<<dim3(2, 4), 256, 0, stream>>>(
      RowDirect{hid, 512}, wt + WT_fin, fin_b, out_main, 256, 512);
}

// Round 9
// 1279.735 us; speedup vs baseline: 2.4136x; 1.1146x over previous
//
#include <hip/hip_runtime.h>
#include <math.h>

// ---- problem constants ----
constexpr int CB = 8, CNT = 64, CD = 256, CKSEL = 16;
constexpr int CNH = 8, CNL = 4, CNP = 4, CDH = 32;
constexpr int CP = 12288, CS = 16320, CQ = 1024, CBQ = 8192, CDFF = 1024;

using short8 = __attribute__((ext_vector_type(8))) short;
using f32x4  = __attribute__((ext_vector_type(4))) float;

__device__ __forceinline__ ushort f2bf(float f) {  // fp32 -> bf16 RNE
  unsigned u = __float_as_uint(f);
  u += 0x7fff + ((u >> 16) & 1);
  return (ushort)(u >> 16);
}
__device__ __forceinline__ float bf2f(ushort u) {
  return __uint_as_float((unsigned)u << 16);
}

// ================= top-k =================
__global__ __launch_bounds__(256) void topk_kernel(const float* __restrict__ c_t,
                                                   float* __restrict__ p_patch,
                                                   float* __restrict__ ref) {
  const int bt = blockIdx.x;  // b*64 + t
  const float* row = c_t + (size_t)bt * CP;
  const int tid = threadIdx.x;
  float lv[16]; int li[16];
#pragma unroll
  for (int j = 0; j < 16; ++j) { lv[j] = -INFINITY; li[j] = 0x7fffffff; }
  for (int s = tid; s < CP; s += 256) {
    float v = row[s];
    if (v > lv[15]) {       // tie keeps earlier (lower) index: strict >
      lv[15] = v; li[15] = s;
#pragma unroll
      for (int j = 15; j > 0; --j) {
        if (lv[j] > lv[j - 1]) {
          float tv = lv[j]; lv[j] = lv[j - 1]; lv[j - 1] = tv;
          int ti = li[j]; li[j] = li[j - 1]; li[j - 1] = ti;
        }
      }
    }
  }
  __shared__ float sv[256 * 16];
  __shared__ int   si[256 * 16];
#pragma unroll
  for (int j = 0; j < 16; ++j) { sv[tid * 16 + j] = lv[j]; si[tid * 16 + j] = li[j]; }
  __syncthreads();
  for (int step = 128; step > 0; step >>= 1) {
    float ov[16]; int oi[16];
    if (tid < step) {
      int ia = 0, ib = 0;
#pragma unroll
      for (int j = 0; j < 16; ++j) {
        bool takeA;
        if (ia >= 16) takeA = false;
        else if (ib >= 16) takeA = true;
        else {
          float av = sv[tid * 16 + ia], bv = sv[(tid + step) * 16 + ib];
          int ai = si[tid * 16 + ia], bi = si[(tid + step) * 16 + ib];
          takeA = (av > bv) || (av == bv && ai < bi);
        }
        if (takeA) { ov[j] = sv[tid * 16 + ia]; oi[j] = si[tid * 16 + ia]; ++ia; }
        else       { ov[j] = sv[(tid + step) * 16 + ib]; oi[j] = si[(tid + step) * 16 + ib]; ++ib; }
      }
    }
    __syncthreads();
    if (tid < step) {
#pragma unroll
      for (int j = 0; j < 16; ++j) { sv[tid * 16 + j] = ov[j]; si[tid * 16 + j] = oi[j]; }
    }
    __syncthreads();
  }
  if (tid < 16) {
    int idx = si[tid];
    float xi = (float)(idx & 127) * 4.0f + 2.0f;   // Wf=128, STRIDE=4
    float yi = (float)(idx >> 7) * 4.0f + 2.0f;
    size_t o = (size_t)bt * 16 + tid;
    p_patch[o * 2 + 0] = xi;
    p_patch[o * 2 + 1] = yi;
    ref[o * 2 + 0] = fminf(fmaxf(xi * (1.0f / 512.0f), 0.f), 1.f);
    ref[o * 2 + 1] = fminf(fmaxf(yi * (1.0f / 384.0f), 0.f), 1.f);
  }
}

// ================= weight transpose + bf16 convert =================
__global__ __launch_bounds__(256) void transpose_cvt(const float* __restrict__ src,
                                                     ushort* __restrict__ dst,
                                                     int K, int N,
                                                     size_t sStride, size_t dStride) {
  src += blockIdx.z * sStride;
  dst += blockIdx.z * dStride;
  __shared__ float t[32][33];
  const int n0 = blockIdx.x * 32, k0 = blockIdx.y * 32;
  const int c = threadIdx.x & 31, r = threadIdx.x >> 5;  // r 0..7
#pragma unroll
  for (int i = 0; i < 4; ++i)
    t[r + i * 8][c] = src[(size_t)(k0 + r + i * 8) * N + n0 + c];
  __syncthreads();
#pragma unroll
  for (int i = 0; i < 4; ++i)
    dst[(size_t)(n0 + r + i * 8) * K + k0 + c] = f2bf(t[c][r + i * 8]);
}

// ================= f_scales gather + bf16 convert (one shot) =================
struct RowVal {  // rows of concat([f4,f8,f16,f32], axis=1): (B, 16320, 256)
  const float* f4; const float* f8; const float* f16; const float* f32;
  __device__ __forceinline__ const float* row(int r) const {
    int b = r / CS, s = r - b * CS;
    if (s < 12288) return f4 + ((size_t)b * 12288 + s) * CD;
    if (s < 15360) return f8 + ((size_t)b * 3072 + (s - 12288)) * CD;
    if (s < 16128) return f16 + ((size_t)b * 768 + (s - 15360)) * CD;
    return f32 + ((size_t)b * 192 + (s - 16128)) * CD;
  }
};

__global__ __launch_bounds__(256) void cvt_fscales(RowVal rv, ushort* __restrict__ dst) {
  size_t t = (size_t)blockIdx.x * 256 + threadIdx.x;   // 8 elements per thread
  size_t off = t * 8;
  int r = (int)(off >> 8);
  int c0 = (int)(off & 255);
  const float* p = rv.row(r) + c0;
  float4 a = *(const float4*)p;
  float4 b = *(const float4*)(p + 4);
  uint4 o;
  o.x = (uint)f2bf(a.x) | ((uint)f2bf(a.y) << 16);
  o.y = (uint)f2bf(a.z) | ((uint)f2bf(a.w) << 16);
  o.z = (uint)f2bf(b.x) | ((uint)f2bf(b.y) << 16);
  o.w = (uint)f2bf(b.z) | ((uint)f2bf(b.w) << 16);
  *(uint4*)(dst + off) = o;
}

// ================= MFMA bf16 GEMM =================
// C[M,N] = A[M,K] @ B[K,N] + bias; A row-major (fp32 or bf16), Bt = B^T bf16 (N x K).
// C fp32 or bf16. BM=BN=128, BK=32, 256 threads (4 waves, each 64x64).
__device__ __forceinline__ short8 ldfrag(const ushort* p) {  // 8 contiguous bf16
  ushort4 lo = *(const ushort4*)p;
  ushort4 hi = *(const ushort4*)(p + 4);
  short8 f;
  f[0] = (short)lo.x; f[1] = (short)lo.y; f[2] = (short)lo.z; f[3] = (short)lo.w;
  f[4] = (short)hi.x; f[5] = (short)hi.y; f[6] = (short)hi.z; f[7] = (short)hi.w;
  return f;
}

template <typename AT, typename CT, bool RELU>
__global__ __launch_bounds__(256) void gemm_mfma(const AT* __restrict__ A,
                                                 const ushort* __restrict__ Bt,
                                                 const float* __restrict__ bias,
                                                 CT* __restrict__ C, int N, int K) {
  __shared__ ushort As[128][40];
  __shared__ ushort Bs[128][40];
  const int tid = threadIdx.x;
  const int lane = tid & 63;
  const int wave = tid >> 6;
  const int wm = (wave >> 1) * 64;
  const int wn = (wave & 1) * 64;
  const int row0 = blockIdx.y * 128, col0 = blockIdx.x * 128;

  const int sr = tid >> 1;           // 0..127
  const int sk = (tid & 1) * 16;     // 0 or 16
  const AT*     arow = A + (size_t)(row0 + sr) * K + sk;
  const ushort* brow = Bt + (size_t)(col0 + sr) * K + sk;

  const int fr = lane & 15;
  const int fk = (lane >> 4) * 8;

  f32x4 acc[4][4] = {};
  for (int k0 = 0; k0 < K; k0 += 32) {
    if constexpr (sizeof(AT) == 4) {   // fp32 A: load + convert
      float4 a0 = *(const float4*)(arow + k0);
      float4 a1 = *(const float4*)(arow + k0 + 4);
      float4 a2 = *(const float4*)(arow + k0 + 8);
      float4 a3 = *(const float4*)(arow + k0 + 12);
      ushort4 ua0 = {f2bf(a0.x), f2bf(a0.y), f2bf(a0.z), f2bf(a0.w)};
      ushort4 ua1 = {f2bf(a1.x), f2bf(a1.y), f2bf(a1.z), f2bf(a1.w)};
      ushort4 ua2 = {f2bf(a2.x), f2bf(a2.y), f2bf(a2.z), f2bf(a2.w)};
      ushort4 ua3 = {f2bf(a3.x), f2bf(a3.y), f2bf(a3.z), f2bf(a3.w)};
      *(ushort4*)&As[sr][sk + 0]  = ua0;
      *(ushort4*)&As[sr][sk + 4]  = ua1;
      *(ushort4*)&As[sr][sk + 8]  = ua2;
      *(ushort4*)&As[sr][sk + 12] = ua3;
    } else {                           // bf16 A: straight copy
      ushort4 ua0 = *(const ushort4*)(arow + k0);
      ushort4 ua1 = *(const ushort4*)(arow + k0 + 4);
      ushort4 ua2 = *(const ushort4*)(arow + k0 + 8);
      ushort4 ua3 = *(const ushort4*)(arow + k0 + 12);
      *(ushort4*)&As[sr][sk + 0]  = ua0;
      *(ushort4*)&As[sr][sk + 4]  = ua1;
      *(ushort4*)&As[sr][sk + 8]  = ua2;
      *(ushort4*)&As[sr][sk + 12] = ua3;
    }
    ushort4 ub0 = *(const ushort4*)(brow + k0);
    ushort4 ub1 = *(const ushort4*)(brow + k0 + 4);
    ushort4 ub2 = *(const ushort4*)(brow + k0 + 8);
    ushort4 ub3 = *(const ushort4*)(brow + k0 + 12);
    *(ushort4*)&Bs[sr][sk + 0]  = ub0;
    *(ushort4*)&Bs[sr][sk + 4]  = ub1;
    *(ushort4*)&Bs[sr][sk + 8]  = ub2;
    *(ushort4*)&Bs[sr][sk + 12] = ub3;
    __syncthreads();

    short8 af[4], bfr[4];
#pragma unroll
    for (int i = 0; i < 4; ++i) {
      af[i]  = ldfrag(&As[wm + i * 16 + fr][fk]);
      bfr[i] = ldfrag(&Bs[wn + i * 16 + fr][fk]);
    }
#pragma unroll
    for (int i = 0; i < 4; ++i)
#pragma unroll
      for (int j = 0; j < 4; ++j)
        acc[i][j] = __builtin_amdgcn_mfma_f32_16x16x32_bf16(af[i], bfr[j], acc[i][j], 0, 0, 0);
    __syncthreads();
  }
  // epilogue: D col = lane&15, row = (lane>>4)*4 + reg   [m89-verified]
  const int orow = row0 + wm + (lane >> 4) * 4;
  const int ocol = col0 + wn + fr;
#pragma unroll
  for (int i = 0; i < 4; ++i)
#pragma unroll
    for (int j = 0; j < 4; ++j) {
      const int cc = ocol + j * 16;
      const float bv = bias[cc];
#pragma unroll
      for (int r = 0; r < 4; ++r) {
        float v = acc[i][j][r] + bv;
        if (RELU) v = fmaxf(v, 0.f);
        if constexpr (sizeof(CT) == 2)
          C[(size_t)(orow + i * 16 + r) * N + cc] = f2bf(v);
        else
          C[(size_t)(orow + i * 16 + r) * N + cc] = v;
      }
    }
}

// ================= small utility kernels =================
__global__ void bcast_rows(const float4* __restrict__ src, float4* __restrict__ dst,
                           int n4, int shift) {
  int i = blockIdx.x * 256 + threadIdx.x;
  if (i >= n4) return;
  int r = i >> 6, j = i & 63;
  dst[i] = src[((size_t)(r >> shift) << 6) + j];
}

__global__ void concat_rows(const float4* __restrict__ s1, const float4* __restrict__ s2,
                            float4* __restrict__ dst, int n4, int shift) {
  int i = blockIdx.x * 256 + threadIdx.x;
  if (i >= n4) return;
  int r = i >> 7, j = i & 127;
  dst[i] = (j < 64) ? s1[((size_t)r << 6) + j]
                    : s2[((size_t)(r >> shift) << 6) + (j - 64)];
}

__global__ void softmax16_kernel(float* __restrict__ aw, int n) {
  int g = blockIdx.x * 256 + threadIdx.x;
  if (g >= n) return;
  float* p = aw + (size_t)g * 16;
  float mx = -INFINITY;
  for (int j = 0; j < 16; ++j) mx = fmaxf(mx, p[j]);
  float s = 0.f;
  for (int j = 0; j < 16; ++j) { float e = expf(p[j] - mx); p[j] = e; s += e; }
  float inv = 1.f / s;
  for (int j = 0; j < 16; ++j) p[j] *= inv;
}

// ================= ms-deform sampling (bf16 val) =================
__global__ __launch_bounds__(256) void msdeform_kernel(const ushort* __restrict__ val,
                                                       const float* __restrict__ off,
                                                       const float* __restrict__ aw,
                                                       const float* __restrict__ ref,
                                                       float* __restrict__ attn_pre) {
  const int r = blockIdx.x;       // b*1024 + t*16 + k
  const int b = r >> 10;
  const int tid = threadIdx.x;
  const int h = tid >> 5, c = tid & 31;
  const float rx = ref[(size_t)r * 2], ry = ref[(size_t)r * 2 + 1];
  const float* offr = off + (size_t)r * 256;
  const float* awr = aw + (size_t)r * 128;
  const ushort* vb = val + (size_t)b * CS * CD;
  float acc = 0.f;
  const int HL[4] = {96, 48, 24, 12}, WL[4] = {128, 64, 32, 16};
  const int ST[4] = {0, 12288, 15360, 16128};
#pragma unroll
  for (int l = 0; l < 4; ++l) {
    const int Hl = HL[l], Wl = WL[l], st = ST[l];
#pragma unroll
    for (int p = 0; p < 4; ++p) {
      int oi = ((h * 4 + l) * 4 + p) * 2;
      float x = rx * (float)Wl + offr[oi] - 0.5f;
      float y = ry * (float)Hl + offr[oi + 1] - 0.5f;
      float w = awr[h * 16 + l * 4 + p];
      float x0f = floorf(x), y0f = floorf(y);
      float lx = x - x0f, ly = y - y0f;
      int x0 = (int)x0f, y0 = (int)y0f;
#pragma unroll
      for (int cy = 0; cy < 2; ++cy)
#pragma unroll
        for (int cx = 0; cx < 2; ++cx) {
          int xi = x0 + cx, yi = y0 + cy;
          if (xi >= 0 && xi < Wl && yi >= 0 && yi < Hl) {
            float wc = (cx ? lx : 1.f - lx) * (cy ? ly : 1.f - ly);
            int rowi = st + yi * Wl + xi;
            acc += w * wc * bf2f(vb[(size_t)rowi * CD + h * 32 + c]);
          }
        }
    }
  }
  attn_pre[(size_t)r * 256 + tid] = acc;
}

// ================= residual + layernorm =================
__global__ __launch_bounds__(256) void resln_kernel(const float* __restrict__ x,
                                                    const float* __restrict__ res,
                                                    const float* __restrict__ g,
                                                    const float* __restrict__ bta,
                                                    float* __restrict__ out) {
  const int r = blockIdx.x, tid = threadIdx.x;
  const size_t off = (size_t)r * 256 + tid;
  float v = x[off] + res[off];
  __shared__ float s1[256], s2[256];
  s1[tid] = v; s2[tid] = v * v;
  __syncthreads();
  for (int st = 128; st > 0; st >>= 1) {
    if (tid < st) { s1[tid] += s1[tid + st]; s2[tid] += s2[tid + st]; }
    __syncthreads();
  }
  float m = s1[0] * (1.f / 256.f);
  float var = s2[0] * (1.f / 256.f) - m * m;
  out[off] = (v - m) * rsqrtf(var + 1e-5f) * g[tid] + bta[tid];
}

// ================= u/s logits =================
__global__ __launch_bounds__(256) void logits_kernel(const float* __restrict__ fused,
                                                     const float* __restrict__ cW, const float* __restrict__ cb,
                                                     const float* __restrict__ sW, const float* __restrict__ sb,
                                                     float* __restrict__ u, float* __restrict__ s) {
  int r = blockIdx.x * 4 + (threadIdx.x >> 6);
  int lane = threadIdx.x & 63;
  const float* row = fused + (size_t)r * 256;
  float su = 0.f, ss = 0.f;
#pragma unroll
  for (int j = 0; j < 4; ++j) {
    float v = row[lane + j * 64];
    su += v * cW[lane + j * 64];
    ss += v * sW[lane + j * 64];
  }
  for (int o = 32; o > 0; o >>= 1) { su += __shfl_down(su, o); ss += __shfl_down(ss, o); }
  if (lane == 0) { u[r] = su + cb[0]; s[r] = ss + sb[0]; }
}

// ================= 16-key attention =================
__global__ __launch_bounds__(256) void attn_kernel(const float* __restrict__ qh,
                                                   const float* __restrict__ kh,
                                                   const float* __restrict__ vh,
                                                   float* __restrict__ o) {
  const int gq = blockIdx.x;     // 0..511
  const int tid = threadIdx.x;
  const int h = tid >> 5, d = tid & 31;
  const float q = qh[(size_t)gq * 256 + h * 32 + d];
  float sc[16];
  float mx = -INFINITY;
#pragma unroll
  for (int k = 0; k < 16; ++k) {
    float s = q * kh[((size_t)gq * 16 + k) * 256 + h * 32 + d];
#pragma unroll
    for (int o2 = 16; o2 > 0; o2 >>= 1) s += __shfl_xor(s, o2);
    s *= 0.17677669529663687f;  // 32^-0.5
    sc[k] = s; mx = fmaxf(mx, s);
  }
  float den = 0.f;
#pragma unroll
  for (int k = 0; k < 16; ++k) { sc[k] = expf(sc[k] - mx); den += sc[k]; }
  float inv = 1.f / den, acc = 0.f;
#pragma unroll
  for (int k = 0; k < 16; ++k)
    acc += sc[k] * vh[((size_t)gq * 16 + k) * 256 + h * 32 + d];
  o[(size_t)gq * 256 + tid] = acc * inv;
}

// ================= workspace layout (floats) =================
constexpr size_t HALF_VAL = (size_t)CB * CS * CD / 2;            // ushort buf in float units
constexpr size_t OFF_FSB  = 0;                                   // bf16 f_scales (CB*CS*CD ushorts)
constexpr size_t OFF_VALB = OFF_FSB + HALF_VAL;                  // bf16 val
constexpr size_t OFF_QK   = OFF_VALB + HALF_VAL;
constexpr size_t OFF_TMP  = OFF_QK + (size_t)CBQ * CD;
constexpr size_t OFF_AW   = OFF_TMP + (size_t)CBQ * CD;
constexpr size_t OFF_ATT  = OFF_AW + (size_t)CBQ * 128;
constexpr size_t OFF_HID  = OFF_ATT + (size_t)CBQ * CD;          // ushort ffn-hidden / float4 concat
constexpr size_t OFF_REF  = OFF_HID + (size_t)CBQ * CDFF;
constexpr size_t OFF_KH   = OFF_REF + (size_t)CBQ * 2;
constexpr size_t OFF_VH   = OFF_KH + (size_t)CBQ * CD;
constexpr size_t OFF_QH   = OFF_VH + (size_t)CBQ * CD;
constexpr size_t OFF_OB   = OFF_QH + 512 * 256;
constexpr size_t OFF_T3   = OFF_OB + 512 * 256;
constexpr size_t OFF_O1   = OFF_T3 + 512 * 256;
constexpr size_t OFF_O2   = OFF_O1 + 512 * 256;
constexpr size_t OFF_FH   = OFF_O2 + 512 * 256;
constexpr size_t OFF_WT   = OFF_FH + 512 * 1024;                 // bf16 weight region

// bf16 weight sub-offsets (ushort units within the WT region)
constexpr size_t WT_vW    = 0;              // 3 x 256x256
constexpr size_t WT_off   = 196608;         // 3 x 256x256
constexpr size_t WT_attw  = 393216;         // 3 x 128x256
constexpr size_t WT_oW    = 491520;         // 3 x 256x256
constexpr size_t WT_ffn1  = 688128;         // 3 x 1024x256
constexpr size_t WT_ffn2  = 1474560;        // 3 x 256x1024
constexpr size_t WT_fus   = 2260992;        // 256x512
constexpr size_t WT_fq    = 2392064;        // 256x256
constexpr size_t WT_fk    = 2457600;
constexpr size_t WT_fv    = 2523136;
constexpr size_t WT_fo    = 2588672;
constexpr size_t WT_fffn1 = 2654208;        // 1024x256
constexpr size_t WT_fffn2 = 2916352;        // 256x1024
constexpr size_t WT_fin   = 3178496;        // 256x512
constexpr size_t WT_TOTAL = 3309568;        // ushorts
constexpr size_t WS_NEED  = OFF_WT + (WT_TOTAL + 1) / 2;         // floats

extern "C" void kernel_launch(void* const* d_in, const int* in_sizes, int n_in,
                              void* d_out, int out_size, void* d_ws, size_t ws_size,
                              hipStream_t stream) {
  if (ws_size < WS_NEED * sizeof(float)) return;  // clean fail instead of OOB

  const float* q_t    = (const float*)d_in[0];
  const float* f4     = (const float*)d_in[1];
  const float* f8     = (const float*)d_in[2];
  const float* f16    = (const float*)d_in[3];
  const float* f32p   = (const float*)d_in[4];
  const float* c_t    = (const float*)d_in[5];
  const float* off_W  = (const float*)d_in[6];
  const float* off_b  = (const float*)d_in[7];
  const float* attw_W = (const float*)d_in[8];
  const float* attw_b = (const float*)d_in[9];
  const float* vW     = (const float*)d_in[10];
  const float* vb     = (const float*)d_in[11];
  const float* oW     = (const float*)d_in[12];
  const float* ob     = (const float*)d_in[13];
  const float* ln1_g  = (const float*)d_in[14];
  const float* ln1_b  = (const float*)d_in[15];
  const float* ffn1_W = (const float*)d_in[16];
  const float* ffn1_b = (const float*)d_in[17];
  const float* ffn2_W = (const float*)d_in[18];
  const float* ffn2_b = (const float*)d_in[19];
  const float* ln2_g  = (const float*)d_in[20];
  const float* ln2_b  = (const float*)d_in[21];
  const float* fq_W   = (const float*)d_in[22];
  const float* fq_b   = (const float*)d_in[23];
  const float* fk_W   = (const float*)d_in[24];
  const float* fk_b   = (const float*)d_in[25];
  const float* fv_W   = (const float*)d_in[26];
  const float* fv_b   = (const float*)d_in[27];
  const float* fo_W   = (const float*)d_in[28];
  const float* fo_b   = (const float*)d_in[29];
  const float* fln1_g = (const float*)d_in[30];
  const float* fln1_b = (const float*)d_in[31];
  const float* fffn1_W= (const float*)d_in[32];
  const float* fffn1_b= (const float*)d_in[33];
  const float* fffn2_W= (const float*)d_in[34];
  const float* fffn2_b= (const float*)d_in[35];
  const float* fln2_g = (const float*)d_in[36];
  const float* fln2_b = (const float*)d_in[37];
  const float* fus_W  = (const float*)d_in[38];
  const float* fus_b  = (const float*)d_in[39];
  const float* fin_W  = (const float*)d_in[40];
  const float* fin_b  = (const float*)d_in[41];
  const float* cert_W = (const float*)d_in[42];
  const float* cert_b = (const float*)d_in[43];
  const float* sc_W   = (const float*)d_in[44];
  const float* sc_b   = (const float*)d_in[45];

  float* ws = (float*)d_ws;
  float* out = (float*)d_out;

  ushort* fsb  = (ushort*)(ws + OFF_FSB);   // bf16 f_scales
  ushort* valb = (ushort*)(ws + OFF_VALB);  // bf16 val
  float* qk    = ws + OFF_QK;
  float* tmp   = ws + OFF_TMP;
  float* awb   = ws + OFF_AW;
  float* attp  = ws + OFF_ATT;   // also "fused"
  ushort* hidb = (ushort*)(ws + OFF_HID);   // bf16 ffn hidden
  float* catb  = ws + OFF_HID;              // float concat buffer (same region, disjoint in time)
  float* ref   = ws + OFF_REF;
  float* kh    = ws + OFF_KH;
  float* vh    = ws + OFF_VH;
  float* qh    = ws + OFF_QH;
  float* obuf  = ws + OFF_OB;
  float* t3    = ws + OFF_T3;
  float* o1    = ws + OFF_O1;
  float* o2    = ws + OFF_O2;
  ushort* fhidb= (ushort*)(ws + OFF_FH);
  ushort* wt   = (ushort*)(ws + OFF_WT);

  float* out_main = out;               // 512*256
  float* out_pp   = out + 131072;      // (B,NT,K,2)
  float* out_u    = out + 147456;      // (B,NT,K)
  float* out_s    = out + 155648;

  // 0a) weight transpose+convert pre-pass (bf16 N x K)
  {
    auto T = [&](const float* src, size_t wtOff, int K_, int N_, int cnt, size_t sStr, size_t dStr) {
      transpose_cvt<<<dim3(N_ / 32, K_ / 32, cnt), 256, 0, stream>>>(src, wt + wtOff, K_, N_, sStr, dStr);
    };
    T(vW,      WT_vW,    256, 256,  3, 65536, 65536);
    T(off_W,   WT_off,   256, 256,  3, 65536, 65536);
    T(attw_W,  WT_attw,  256, 128,  3, 32768, 32768);
    T(oW,      WT_oW,    256, 256,  3, 65536, 65536);
    T(ffn1_W,  WT_ffn1,  256, 1024, 3, 262144, 262144);
    T(ffn2_W,  WT_ffn2,  1024, 256, 3, 262144, 262144);
    T(fus_W,   WT_fus,   512, 256,  1, 0, 0);
    T(fq_W,    WT_fq,    256, 256,  1, 0, 0);
    T(fk_W,    WT_fk,    256, 256,  1, 0, 0);
    T(fv_W,    WT_fv,    256, 256,  1, 0, 0);
    T(fo_W,    WT_fo,    256, 256,  1, 0, 0);
    T(fffn1_W, WT_fffn1, 256, 1024, 1, 0, 0);
    T(fffn2_W, WT_fffn2, 1024, 256, 1, 0, 0);
    T(fin_W,   WT_fin,   512, 256,  1, 0, 0);
  }
  // 0b) f_scales -> contiguous bf16 (one shot, reused by all 3 val GEMMs)
  cvt_fscales<<<CB * CS * CD / 8 / 256, 256, 0, stream>>>(RowVal{f4, f8, f16, f32p}, fsb);

  // 1) top-k -> p_patch, ref
  topk_kernel<<<CB * CNT, 256, 0, stream>>>(c_t, out_pp, ref);

  // 2) qk init: broadcast q_t rows 16x
  {
    int n4 = CBQ * 64;
    bcast_rows<<<(n4 + 255) / 256, 256, 0, stream>>>((const float4*)q_t, (float4*)qk, n4, 4);
  }

  // 3) refinement layers
  for (int l = 0; l < 3; ++l) {
    // val = f_scales @ vW[l] + vb[l]   (130560 x 256, K=256) — bf16 in, bf16 out
    gemm_mfma<ushort, ushort, false><<<dim3(2, 1020), 256, 0, stream>>>(
        fsb, wt + WT_vW + (size_t)l * 65536, vb + l * CD, valb, 256, 256);
    // off = qk @ off_W[l] + off_b[l]   (8192 x 256)
    gemm_mfma<float, float, false><<<dim3(2, 64), 256, 0, stream>>>(
        qk, wt + WT_off + (size_t)l * 65536, off_b + l * 256, tmp, 256, 256);
    // aw logits = qk @ attw_W[l] + attw_b[l]   (8192 x 128)
    gemm_mfma<float, float, false><<<dim3(1, 64), 256, 0, stream>>>(
        qk, wt + WT_attw + (size_t)l * 32768, attw_b + l * 128, awb, 128, 256);
    softmax16_kernel<<<(CBQ * CNH + 255) / 256, 256, 0, stream>>>(awb, CBQ * CNH);
    msdeform_kernel<<<CBQ, 256, 0, stream>>>(valb, tmp, awb, ref, attp);
    // o-proj   (8192 x 256)
    gemm_mfma<float, float, false><<<dim3(2, 64), 256, 0, stream>>>(
        attp, wt + WT_oW + (size_t)l * 65536, ob + l * CD, tmp, 256, 256);
    resln_kernel<<<CBQ, 256, 0, stream>>>(tmp, qk, ln1_g + l * CD, ln1_b + l * CD, qk);
    // ffn1 (8192 x 1024, relu, bf16 out), ffn2 (8192 x 256, K=1024, bf16 in)
    gemm_mfma<float, ushort, true><<<dim3(8, 64), 256, 0, stream>>>(
        qk, wt + WT_ffn1 + (size_t)l * 262144, ffn1_b + l * CDFF, hidb, 1024, 256);
    gemm_mfma<ushort, float, false><<<dim3(2, 64), 256, 0, stream>>>(
        hidb, wt + WT_ffn2 + (size_t)l * 262144, ffn2_b + l * CD, tmp, 256, 1024);
    resln_kernel<<<CBQ, 256, 0, stream>>>(tmp, qk, ln2_g + l * CD, ln2_b + l * CD, qk);
  }

  // 4) fusion: cat([qk, q_bcast]) @ fus_W + fus_b
  {
    int n4 = CBQ * 128;
    concat_rows<<<(n4 + 255) / 256, 256, 0, stream>>>((const float4*)qk, (const float4*)q_t,
                                                      (float4*)catb, n4, 4);
  }
  gemm_mfma<float, float, false><<<dim3(2, 64), 256, 0, stream>>>(
      catb, wt + WT_fus, fus_b, attp, 256, 512);  // attp = fused

  // 5) u/s logits
  logits_kernel<<<CBQ / 4, 256, 0, stream>>>(attp, cert_W, cert_b, sc_W, sc_b, out_u, out_s);

  // 6) single-query attention over K=16
  gemm_mfma<float, float, false><<<dim3(2, 4), 256, 0, stream>>>(
      q_t, wt + WT_fq, fq_b, qh, 256, 256);
  gemm_mfma<float, float, false><<<dim3(2, 64), 256, 0, stream>>>(
      attp, wt + WT_fk, fk_b, kh, 256, 256);
  gemm_mfma<float, float, false><<<dim3(2, 64), 256, 0, stream>>>(
      attp, wt + WT_fv, fv_b, vh, 256, 256);
  attn_kernel<<<512, 256, 0, stream>>>(qh, kh, vh, obuf);

  // 7) o = LN(qf + o@fo_W + fo_b)
  gemm_mfma<float, float, false><<<dim3(2, 4), 256, 0, stream>>>(
      obuf, wt + WT_fo, fo_b, t3, 256, 256);
  resln_kernel<<<512, 256, 0, stream>>>(t3, q_t, fln1_g, fln1_b, o1);

  // 8) final FFN + LN
  gemm_mfma<float, ushort, true><<<dim3(8, 4), 256, 0, stream>>>(
      o1, wt + WT_fffn1, fffn1_b, fhidb, 1024, 256);
  gemm_mfma<ushort, float, false><<<dim3(2, 4), 256, 0, stream>>>(
      fhidb, wt + WT_fffn2, fffn2_b, t3, 256, 1024);
  resln_kernel<<<512, 256, 0, stream>>>(t3, o1, fln2_g, fln2_b, o2);

  // 9) out = cat([o2, qf]) @ fin_W + fin_b
  {
    int n4 = 512 * 128;
    concat_rows<<<(n4 + 255) / 256, 256, 0, stream>>>((const float4*)o2, (const float4*)q_t,
                                                      (float4*)catb, n4, 0);
  }
  gemm_mfma<float, float, false><<<dim3(2, 4), 256, 0, stream>>>(
      catb, wt + WT_fin, fin_b, out_main, 256, 512);
}

// Round 10
// 1068.748 us; speedup vs baseline: 2.8901x; 1.1974x over previous
//
#include <hip/hip_runtime.h>
#include <math.h>

// ---- problem constants ----
constexpr int CB = 8, CNT = 64, CD = 256, CKSEL = 16;
constexpr int CNH = 8, CNL = 4, CNP = 4, CDH = 32;
constexpr int CP = 12288, CS = 16320, CQ = 1024, CBQ = 8192, CDFF = 1024;

using short8 = __attribute__((ext_vector_type(8))) short;
using f32x4  = __attribute__((ext_vector_type(4))) float;

__device__ __forceinline__ ushort f2bf(float f) {  // fp32 -> bf16 RNE
  unsigned u = __float_as_uint(f);
  u += 0x7fff + ((u >> 16) & 1);
  return (ushort)(u >> 16);
}
__device__ __forceinline__ float bf2f(ushort u) {
  return __uint_as_float((unsigned)u << 16);
}

// ================= top-k =================
__global__ __launch_bounds__(256) void topk_kernel(const float* __restrict__ c_t,
                                                   float* __restrict__ p_patch,
                                                   float* __restrict__ ref) {
  const int bt = blockIdx.x;  // b*64 + t
  const float* row = c_t + (size_t)bt * CP;
  const int tid = threadIdx.x;
  float lv[16]; int li[16];
#pragma unroll
  for (int j = 0; j < 16; ++j) { lv[j] = -INFINITY; li[j] = 0x7fffffff; }
  for (int s = tid; s < CP; s += 256) {
    float v = row[s];
    if (v > lv[15]) {       // tie keeps earlier (lower) index: strict >
      lv[15] = v; li[15] = s;
#pragma unroll
      for (int j = 15; j > 0; --j) {
        if (lv[j] > lv[j - 1]) {
          float tv = lv[j]; lv[j] = lv[j - 1]; lv[j - 1] = tv;
          int ti = li[j]; li[j] = li[j - 1]; li[j - 1] = ti;
        }
      }
    }
  }
  __shared__ float sv[256 * 16];
  __shared__ int   si[256 * 16];
#pragma unroll
  for (int j = 0; j < 16; ++j) { sv[tid * 16 + j] = lv[j]; si[tid * 16 + j] = li[j]; }
  __syncthreads();
  for (int step = 128; step > 0; step >>= 1) {
    float ov[16]; int oi[16];
    if (tid < step) {
      int ia = 0, ib = 0;
#pragma unroll
      for (int j = 0; j < 16; ++j) {
        bool takeA;
        if (ia >= 16) takeA = false;
        else if (ib >= 16) takeA = true;
        else {
          float av = sv[tid * 16 + ia], bv = sv[(tid + step) * 16 + ib];
          int ai = si[tid * 16 + ia], bi = si[(tid + step) * 16 + ib];
          takeA = (av > bv) || (av == bv && ai < bi);
        }
        if (takeA) { ov[j] = sv[tid * 16 + ia]; oi[j] = si[tid * 16 + ia]; ++ia; }
        else       { ov[j] = sv[(tid + step) * 16 + ib]; oi[j] = si[(tid + step) * 16 + ib]; ++ib; }
      }
    }
    __syncthreads();
    if (tid < step) {
#pragma unroll
      for (int j = 0; j < 16; ++j) { sv[tid * 16 + j] = ov[j]; si[tid * 16 + j] = oi[j]; }
    }
    __syncthreads();
  }
  if (tid < 16) {
    int idx = si[tid];
    float xi = (float)(idx & 127) * 4.0f + 2.0f;   // Wf=128, STRIDE=4
    float yi = (float)(idx >> 7) * 4.0f + 2.0f;
    size_t o = (size_t)bt * 16 + tid;
    p_patch[o * 2 + 0] = xi;
    p_patch[o * 2 + 1] = yi;
    ref[o * 2 + 0] = fminf(fmaxf(xi * (1.0f / 512.0f), 0.f), 1.f);
    ref[o * 2 + 1] = fminf(fmaxf(yi * (1.0f / 384.0f), 0.f), 1.f);
  }
}

// ================= weight transpose + bf16 convert =================
__global__ __launch_bounds__(256) void transpose_cvt(const float* __restrict__ src,
                                                     ushort* __restrict__ dst,
                                                     int K, int N,
                                                     size_t sStride, size_t dStride) {
  src += blockIdx.z * sStride;
  dst += blockIdx.z * dStride;
  __shared__ float t[32][33];
  const int n0 = blockIdx.x * 32, k0 = blockIdx.y * 32;
  const int c = threadIdx.x & 31, r = threadIdx.x >> 5;  // r 0..7
#pragma unroll
  for (int i = 0; i < 4; ++i)
    t[r + i * 8][c] = src[(size_t)(k0 + r + i * 8) * N + n0 + c];
  __syncthreads();
#pragma unroll
  for (int i = 0; i < 4; ++i)
    dst[(size_t)(n0 + r + i * 8) * K + k0 + c] = f2bf(t[c][r + i * 8]);
}

// ================= bias concat =================
__global__ void concat_bias(const float* __restrict__ a, const float* __restrict__ b,
                            float* __restrict__ dst, int na, int nb) {
  int i = blockIdx.x * 256 + threadIdx.x;
  if (i < na) dst[i] = a[i];
  else if (i < na + nb) dst[i] = b[i - na];
}

// ================= f_scales gather + bf16 convert (one shot) =================
struct RowVal {  // rows of concat([f4,f8,f16,f32], axis=1): (B, 16320, 256)
  const float* f4; const float* f8; const float* f16; const float* f32;
  __device__ __forceinline__ const float* row(int r) const {
    int b = r / CS, s = r - b * CS;
    if (s < 12288) return f4 + ((size_t)b * 12288 + s) * CD;
    if (s < 15360) return f8 + ((size_t)b * 3072 + (s - 12288)) * CD;
    if (s < 16128) return f16 + ((size_t)b * 768 + (s - 15360)) * CD;
    return f32 + ((size_t)b * 192 + (s - 16128)) * CD;
  }
};

__global__ __launch_bounds__(256) void cvt_fscales(RowVal rv, ushort* __restrict__ dst) {
  size_t t = (size_t)blockIdx.x * 256 + threadIdx.x;   // 8 elements per thread
  size_t off = t * 8;
  int r = (int)(off >> 8);
  int c0 = (int)(off & 255);
  const float* p = rv.row(r) + c0;
  float4 a = *(const float4*)p;
  float4 b = *(const float4*)(p + 4);
  uint4 o;
  o.x = (uint)f2bf(a.x) | ((uint)f2bf(a.y) << 16);
  o.y = (uint)f2bf(a.z) | ((uint)f2bf(a.w) << 16);
  o.z = (uint)f2bf(b.x) | ((uint)f2bf(b.y) << 16);
  o.w = (uint)f2bf(b.z) | ((uint)f2bf(b.w) << 16);
  *(uint4*)(dst + off) = o;
}

// ================= MFMA bf16 GEMM =================
__device__ __forceinline__ short8 ldfrag(const ushort* p) {  // 8 contiguous bf16
  ushort4 lo = *(const ushort4*)p;
  ushort4 hi = *(const ushort4*)(p + 4);
  short8 f;
  f[0] = (short)lo.x; f[1] = (short)lo.y; f[2] = (short)lo.z; f[3] = (short)lo.w;
  f[4] = (short)hi.x; f[5] = (short)hi.y; f[6] = (short)hi.z; f[7] = (short)hi.w;
  return f;
}

template <typename AT, typename CT, bool RELU>
__global__ __launch_bounds__(256) void gemm_mfma(const AT* __restrict__ A,
                                                 const ushort* __restrict__ Bt,
                                                 const float* __restrict__ bias,
                                                 CT* __restrict__ C, int N, int K) {
  __shared__ ushort As[128][40];
  __shared__ ushort Bs[128][40];
  const int tid = threadIdx.x;
  const int lane = tid & 63;
  const int wave = tid >> 6;
  const int wm = (wave >> 1) * 64;
  const int wn = (wave & 1) * 64;
  const int row0 = blockIdx.y * 128, col0 = blockIdx.x * 128;

  const int sr = tid >> 1;           // 0..127
  const int sk = (tid & 1) * 16;     // 0 or 16
  const AT*     arow = A + (size_t)(row0 + sr) * K + sk;
  const ushort* brow = Bt + (size_t)(col0 + sr) * K + sk;

  const int fr = lane & 15;
  const int fk = (lane >> 4) * 8;

  f32x4 acc[4][4] = {};
  for (int k0 = 0; k0 < K; k0 += 32) {
    if constexpr (sizeof(AT) == 4) {   // fp32 A: load + convert
      float4 a0 = *(const float4*)(arow + k0);
      float4 a1 = *(const float4*)(arow + k0 + 4);
      float4 a2 = *(const float4*)(arow + k0 + 8);
      float4 a3 = *(const float4*)(arow + k0 + 12);
      ushort4 ua0 = {f2bf(a0.x), f2bf(a0.y), f2bf(a0.z), f2bf(a0.w)};
      ushort4 ua1 = {f2bf(a1.x), f2bf(a1.y), f2bf(a1.z), f2bf(a1.w)};
      ushort4 ua2 = {f2bf(a2.x), f2bf(a2.y), f2bf(a2.z), f2bf(a2.w)};
      ushort4 ua3 = {f2bf(a3.x), f2bf(a3.y), f2bf(a3.z), f2bf(a3.w)};
      *(ushort4*)&As[sr][sk + 0]  = ua0;
      *(ushort4*)&As[sr][sk + 4]  = ua1;
      *(ushort4*)&As[sr][sk + 8]  = ua2;
      *(ushort4*)&As[sr][sk + 12] = ua3;
    } else {                           // bf16 A: straight copy
      ushort4 ua0 = *(const ushort4*)(arow + k0);
      ushort4 ua1 = *(const ushort4*)(arow + k0 + 4);
      ushort4 ua2 = *(const ushort4*)(arow + k0 + 8);
      ushort4 ua3 = *(const ushort4*)(arow + k0 + 12);
      *(ushort4*)&As[sr][sk + 0]  = ua0;
      *(ushort4*)&As[sr][sk + 4]  = ua1;
      *(ushort4*)&As[sr][sk + 8]  = ua2;
      *(ushort4*)&As[sr][sk + 12] = ua3;
    }
    ushort4 ub0 = *(const ushort4*)(brow + k0);
    ushort4 ub1 = *(const ushort4*)(brow + k0 + 4);
    ushort4 ub2 = *(const ushort4*)(brow + k0 + 8);
    ushort4 ub3 = *(const ushort4*)(brow + k0 + 12);
    *(ushort4*)&Bs[sr][sk + 0]  = ub0;
    *(ushort4*)&Bs[sr][sk + 4]  = ub1;
    *(ushort4*)&Bs[sr][sk + 8]  = ub2;
    *(ushort4*)&Bs[sr][sk + 12] = ub3;
    __syncthreads();

    short8 af[4], bfr[4];
#pragma unroll
    for (int i = 0; i < 4; ++i) {
      af[i]  = ldfrag(&As[wm + i * 16 + fr][fk]);
      bfr[i] = ldfrag(&Bs[wn + i * 16 + fr][fk]);
    }
#pragma unroll
    for (int i = 0; i < 4; ++i)
#pragma unroll
      for (int j = 0; j < 4; ++j)
        acc[i][j] = __builtin_amdgcn_mfma_f32_16x16x32_bf16(af[i], bfr[j], acc[i][j], 0, 0, 0);
    __syncthreads();
  }
  // epilogue: D col = lane&15, row = (lane>>4)*4 + reg   [m89-verified]
  const int orow = row0 + wm + (lane >> 4) * 4;
  const int ocol = col0 + wn + fr;
#pragma unroll
  for (int i = 0; i < 4; ++i)
#pragma unroll
    for (int j = 0; j < 4; ++j) {
      const int cc = ocol + j * 16;
      const float bv = bias[cc];
#pragma unroll
      for (int r = 0; r < 4; ++r) {
        float v = acc[i][j][r] + bv;
        if (RELU) v = fmaxf(v, 0.f);
        if constexpr (sizeof(CT) == 2)
          C[(size_t)(orow + i * 16 + r) * N + cc] = f2bf(v);
        else
          C[(size_t)(orow + i * 16 + r) * N + cc] = v;
      }
    }
}

// ================= small utility kernels =================
__global__ void bcast_rows(const float4* __restrict__ src, float4* __restrict__ dst,
                           int n4, int shift) {
  int i = blockIdx.x * 256 + threadIdx.x;
  if (i >= n4) return;
  int r = i >> 6, j = i & 63;
  dst[i] = src[((size_t)(r >> shift) << 6) + j];
}

__global__ void concat_rows(const float4* __restrict__ s1, const float4* __restrict__ s2,
                            float4* __restrict__ dst, int n4, int shift) {
  int i = blockIdx.x * 256 + threadIdx.x;
  if (i >= n4) return;
  int r = i >> 7, j = i & 127;
  dst[i] = (j < 64) ? s1[((size_t)r << 6) + j]
                    : s2[((size_t)(r >> shift) << 6) + (j - 64)];
}

// ================= ms-deform sampling v2 =================
// grid = CBQ/4 blocks x 256 threads; one 64-lane wave per query.
// lane = (head h = lane>>3, channel-quad c4 = (lane&7)*4). ushort4 loads (8B).
// oab[r][384]: cols 0..255 = off (h*32+l*8+p*2), 256..383 = aw logits (h*16+l*4+p).
// Softmax over the 16 logits computed in-kernel (identical math to reference).
__global__ __launch_bounds__(256) void msdeform_kernel(const ushort* __restrict__ val,
                                                       const float* __restrict__ oab,
                                                       const float* __restrict__ ref,
                                                       float* __restrict__ attn_pre) {
  const int tid = threadIdx.x;
  const int r = blockIdx.x * 4 + (tid >> 6);
  const int b = r >> 10;
  const int lane = tid & 63;
  const int h = lane >> 3;
  const int c4 = (lane & 7) * 4;
  const float rx = ref[(size_t)r * 2], ry = ref[(size_t)r * 2 + 1];
  const float* oa = oab + (size_t)r * 384;
  const ushort* vb = val + (size_t)b * CS * CD + h * 32 + c4;

  // per-head softmax (redundant across the 8 lanes of a head — cheap)
  float ex[16];
  float mx = -INFINITY;
#pragma unroll
  for (int j = 0; j < 16; ++j) { ex[j] = oa[256 + h * 16 + j]; mx = fmaxf(mx, ex[j]); }
  float den = 0.f;
#pragma unroll
  for (int j = 0; j < 16; ++j) { ex[j] = expf(ex[j] - mx); den += ex[j]; }
  const float inv = 1.f / den;

  float a0 = 0.f, a1 = 0.f, a2 = 0.f, a3 = 0.f;
  const int HL[4] = {96, 48, 24, 12}, WL[4] = {128, 64, 32, 16};
  const int ST[4] = {0, 12288, 15360, 16128};
#pragma unroll
  for (int l = 0; l < 4; ++l) {
    const int Hl = HL[l], Wl = WL[l], st = ST[l];
#pragma unroll
    for (int p = 0; p < 4; ++p) {
      const int oi = h * 32 + l * 8 + p * 2;
      float x = rx * (float)Wl + oa[oi] - 0.5f;
      float y = ry * (float)Hl + oa[oi + 1] - 0.5f;
      float w = ex[l * 4 + p] * inv;
      float x0f = floorf(x), y0f = floorf(y);
      float lx = x - x0f, ly = y - y0f;
      int x0 = (int)x0f, y0 = (int)y0f;
#pragma unroll
      for (int cy = 0; cy < 2; ++cy)
#pragma unroll
        for (int cx = 0; cx < 2; ++cx) {
          int xi = x0 + cx, yi = y0 + cy;
          if (xi >= 0 && xi < Wl && yi >= 0 && yi < Hl) {
            float wc = w * (cx ? lx : 1.f - lx) * (cy ? ly : 1.f - ly);
            ushort4 v = *(const ushort4*)(vb + (size_t)(st + yi * Wl + xi) * CD);
            a0 += wc * bf2f(v.x);
            a1 += wc * bf2f(v.y);
            a2 += wc * bf2f(v.z);
            a3 += wc * bf2f(v.w);
          }
        }
    }
  }
  float4 o = {a0, a1, a2, a3};
  *(float4*)(attn_pre + (size_t)r * 256 + h * 32 + c4) = o;
}

// ================= residual + layernorm =================
__global__ __launch_bounds__(256) void resln_kernel(const float* __restrict__ x,
                                                    const float* __restrict__ res,
                                                    const float* __restrict__ g,
                                                    const float* __restrict__ bta,
                                                    float* __restrict__ out) {
  const int r = blockIdx.x, tid = threadIdx.x;
  const size_t off = (size_t)r * 256 + tid;
  float v = x[off] + res[off];
  __shared__ float s1[256], s2[256];
  s1[tid] = v; s2[tid] = v * v;
  __syncthreads();
  for (int st = 128; st > 0; st >>= 1) {
    if (tid < st) { s1[tid] += s1[tid + st]; s2[tid] += s2[tid + st]; }
    __syncthreads();
  }
  float m = s1[0] * (1.f / 256.f);
  float var = s2[0] * (1.f / 256.f) - m * m;
  out[off] = (v - m) * rsqrtf(var + 1e-5f) * g[tid] + bta[tid];
}

// ================= u/s logits =================
__global__ __launch_bounds__(256) void logits_kernel(const float* __restrict__ fused,
                                                     const float* __restrict__ cW, const float* __restrict__ cb,
                                                     const float* __restrict__ sW, const float* __restrict__ sb,
                                                     float* __restrict__ u, float* __restrict__ s) {
  int r = blockIdx.x * 4 + (threadIdx.x >> 6);
  int lane = threadIdx.x & 63;
  const float* row = fused + (size_t)r * 256;
  float su = 0.f, ss = 0.f;
#pragma unroll
  for (int j = 0; j < 4; ++j) {
    float v = row[lane + j * 64];
    su += v * cW[lane + j * 64];
    ss += v * sW[lane + j * 64];
  }
  for (int o = 32; o > 0; o >>= 1) { su += __shfl_down(su, o); ss += __shfl_down(ss, o); }
  if (lane == 0) { u[r] = su + cb[0]; s[r] = ss + sb[0]; }
}

// ================= 16-key attention (combined kv [r][512]) =================
__global__ __launch_bounds__(256) void attn_kernel(const float* __restrict__ qh,
                                                   const float* __restrict__ kvb,
                                                   float* __restrict__ o) {
  const int gq = blockIdx.x;     // 0..511
  const int tid = threadIdx.x;
  const int h = tid >> 5, d = tid & 31;
  const float q = qh[(size_t)gq * 256 + h * 32 + d];
  float sc[16];
  float mx = -INFINITY;
#pragma unroll
  for (int k = 0; k < 16; ++k) {
    float s = q * kvb[((size_t)gq * 16 + k) * 512 + h * 32 + d];
#pragma unroll
    for (int o2 = 16; o2 > 0; o2 >>= 1) s += __shfl_xor(s, o2);
    s *= 0.17677669529663687f;  // 32^-0.5
    sc[k] = s; mx = fmaxf(mx, s);
  }
  float den = 0.f;
#pragma unroll
  for (int k = 0; k < 16; ++k) { sc[k] = expf(sc[k] - mx); den += sc[k]; }
  float inv = 1.f / den, acc = 0.f;
#pragma unroll
  for (int k = 0; k < 16; ++k)
    acc += sc[k] * kvb[((size_t)gq * 16 + k) * 512 + 256 + h * 32 + d];
  o[(size_t)gq * 256 + tid] = acc * inv;
}

// ================= workspace layout (floats) =================
constexpr size_t HALF_VAL = (size_t)CB * CS * CD / 2;            // ushort buf in float units
constexpr size_t OFF_FSB  = 0;                                   // bf16 f_scales
constexpr size_t OFF_VALB = OFF_FSB + HALF_VAL;                  // bf16 val
constexpr size_t OFF_QK   = OFF_VALB + HALF_VAL;
constexpr size_t OFF_TMP  = OFF_QK + (size_t)CBQ * CD;
constexpr size_t OFF_OAB  = OFF_TMP + (size_t)CBQ * CD;          // [8192][384] off+aw
constexpr size_t OFF_ATT  = OFF_OAB + (size_t)CBQ * 384;
constexpr size_t OFF_HID  = OFF_ATT + (size_t)CBQ * CD;          // bf16 hidden OR fp32 concat (disjoint in time)
constexpr size_t OFF_REF  = OFF_HID + (size_t)CBQ * 512;
constexpr size_t OFF_KVB  = OFF_REF + (size_t)CBQ * 2;           // [8192][512] k|v
constexpr size_t OFF_QH   = OFF_KVB + (size_t)CBQ * 512;
constexpr size_t OFF_OB   = OFF_QH + 512 * 256;
constexpr size_t OFF_T3   = OFF_OB + 512 * 256;
constexpr size_t OFF_O1   = OFF_T3 + 512 * 256;
constexpr size_t OFF_O2   = OFF_O1 + 512 * 256;
constexpr size_t OFF_FH   = OFF_O2 + 512 * 256;                  // bf16 512x1024 = 262144 floats
constexpr size_t OFF_CB   = OFF_FH + 262144;                     // concat biases: 3*384 + 512
constexpr size_t OFF_WT   = OFF_CB + 2048;

// bf16 weight sub-offsets (ushort units within WT region)
constexpr size_t WT_vW    = 0;              // 3 x 256x256
constexpr size_t WT_oab   = 196608;         // 3 x (256+128)x256
constexpr size_t WT_oW    = 491520;         // 3 x 256x256
constexpr size_t WT_ffn1  = 688128;         // 3 x 1024x256
constexpr size_t WT_ffn2  = 1474560;        // 3 x 256x1024
constexpr size_t WT_fus   = 2260992;        // 256x512
constexpr size_t WT_fq    = 2392064;        // 256x256
constexpr size_t WT_fkv   = 2457600;        // (256+256)x256
constexpr size_t WT_fo    = 2588672;        // 256x256
constexpr size_t WT_fffn1 = 2654208;        // 1024x256
constexpr size_t WT_fffn2 = 2916352;        // 256x1024
constexpr size_t WT_fin   = 3178496;        // 256x512
constexpr size_t WT_TOTAL = 3309568;        // ushorts
constexpr size_t WS_NEED  = OFF_WT + (WT_TOTAL + 1) / 2;         // floats

extern "C" void kernel_launch(void* const* d_in, const int* in_sizes, int n_in,
                              void* d_out, int out_size, void* d_ws, size_t ws_size,
                              hipStream_t stream) {
  if (ws_size < WS_NEED * sizeof(float)) return;  // clean fail instead of OOB

  const float* q_t    = (const float*)d_in[0];
  const float* f4     = (const float*)d_in[1];
  const float* f8     = (const float*)d_in[2];
  const float* f16    = (const float*)d_in[3];
  const float* f32p   = (const float*)d_in[4];
  const float* c_t    = (const float*)d_in[5];
  const float* off_W  = (const float*)d_in[6];
  const float* off_b  = (const float*)d_in[7];
  const float* attw_W = (const float*)d_in[8];
  const float* attw_b = (const float*)d_in[9];
  const float* vW     = (const float*)d_in[10];
  const float* vb     = (const float*)d_in[11];
  const float* oW     = (const float*)d_in[12];
  const float* ob     = (const float*)d_in[13];
  const float* ln1_g  = (const float*)d_in[14];
  const float* ln1_b  = (const float*)d_in[15];
  const float* ffn1_W = (const float*)d_in[16];
  const float* ffn1_b = (const float*)d_in[17];
  const float* ffn2_W = (const float*)d_in[18];
  const float* ffn2_b = (const float*)d_in[19];
  const float* ln2_g  = (const float*)d_in[20];
  const float* ln2_b  = (const float*)d_in[21];
  const float* fq_W   = (const float*)d_in[22];
  const float* fq_b   = (const float*)d_in[23];
  const float* fk_W   = (const float*)d_in[24];
  const float* fk_b   = (const float*)d_in[25];
  const float* fv_W   = (const float*)d_in[26];
  const float* fv_b   = (const float*)d_in[27];
  const float* fo_W   = (const float*)d_in[28];
  const float* fo_b   = (const float*)d_in[29];
  const float* fln1_g = (const float*)d_in[30];
  const float* fln1_b = (const float*)d_in[31];
  const float* fffn1_W= (const float*)d_in[32];
  const float* fffn1_b= (const float*)d_in[33];
  const float* fffn2_W= (const float*)d_in[34];
  const float* fffn2_b= (const float*)d_in[35];
  const float* fln2_g = (const float*)d_in[36];
  const float* fln2_b = (const float*)d_in[37];
  const float* fus_W  = (const float*)d_in[38];
  const float* fus_b  = (const float*)d_in[39];
  const float* fin_W  = (const float*)d_in[40];
  const float* fin_b  = (const float*)d_in[41];
  const float* cert_W = (const float*)d_in[42];
  const float* cert_b = (const float*)d_in[43];
  const float* sc_W   = (const float*)d_in[44];
  const float* sc_b   = (const float*)d_in[45];

  float* ws = (float*)d_ws;
  float* out = (float*)d_out;

  ushort* fsb  = (ushort*)(ws + OFF_FSB);
  ushort* valb = (ushort*)(ws + OFF_VALB);
  float* qk    = ws + OFF_QK;
  float* tmp   = ws + OFF_TMP;
  float* oabuf = ws + OFF_OAB;
  float* attp  = ws + OFF_ATT;              // also "fused"
  ushort* hidb = (ushort*)(ws + OFF_HID);   // bf16 ffn hidden
  float* catb  = ws + OFF_HID;              // fp32 concat buffer (disjoint in time)
  float* ref   = ws + OFF_REF;
  float* kvb   = ws + OFF_KVB;
  float* qh    = ws + OFF_QH;
  float* obuf  = ws + OFF_OB;
  float* t3    = ws + OFF_T3;
  float* o1    = ws + OFF_O1;
  float* o2    = ws + OFF_O2;
  ushort* fhidb= (ushort*)(ws + OFF_FH);
  float* cbias = ws + OFF_CB;               // [3][384] then [512]
  ushort* wt   = (ushort*)(ws + OFF_WT);

  float* out_main = out;               // 512*256
  float* out_pp   = out + 131072;      // (B,NT,K,2)
  float* out_u    = out + 147456;      // (B,NT,K)
  float* out_s    = out + 155648;

  // 0a) weight transpose+convert pre-pass (bf16 N x K)
  {
    auto T = [&](const float* src, size_t wtOff, int K_, int N_, int cnt, size_t sStr, size_t dStr) {
      transpose_cvt<<<dim3(N_ / 32, K_ / 32, cnt), 256, 0, stream>>>(src, wt + wtOff, K_, N_, sStr, dStr);
    };
    T(vW,      WT_vW,    256, 256,  3, 65536, 65536);
    T(off_W,   WT_oab,          256, 256,  3, 65536, 98304);   // rows 0..255 of each layer's 384
    T(attw_W,  WT_oab + 65536,  256, 128,  3, 32768, 98304);   // rows 256..383
    T(oW,      WT_oW,    256, 256,  3, 65536, 65536);
    T(ffn1_W,  WT_ffn1,  256, 1024, 3, 262144, 262144);
    T(ffn2_W,  WT_ffn2,  1024, 256, 3, 262144, 262144);
    T(fus_W,   WT_fus,   512, 256,  1, 0, 0);
    T(fq_W,    WT_fq,    256, 256,  1, 0, 0);
    T(fk_W,    WT_fkv,          256, 256,  1, 0, 0);           // rows 0..255
    T(fv_W,    WT_fkv + 65536,  256, 256,  1, 0, 0);           // rows 256..511
    T(fo_W,    WT_fo,    256, 256,  1, 0, 0);
    T(fffn1_W, WT_fffn1, 256, 1024, 1, 0, 0);
    T(fffn2_W, WT_fffn2, 1024, 256, 1, 0, 0);
    T(fin_W,   WT_fin,   512, 256,  1, 0, 0);
  }
  // 0b) concat biases: [3][384] off_b|attw_b, then [512] fk_b|fv_b
  for (int l = 0; l < 3; ++l)
    concat_bias<<<2, 256, 0, stream>>>(off_b + l * 256, attw_b + l * 128,
                                       cbias + l * 384, 256, 128);
  concat_bias<<<2, 256, 0, stream>>>(fk_b, fv_b, cbias + 1152, 256, 256);

  // 0c) f_scales -> contiguous bf16 (one shot)
  cvt_fscales<<<CB * CS * CD / 8 / 256, 256, 0, stream>>>(RowVal{f4, f8, f16, f32p}, fsb);

  // 1) top-k -> p_patch, ref
  topk_kernel<<<CB * CNT, 256, 0, stream>>>(c_t, out_pp, ref);

  // 2) qk init: broadcast q_t rows 16x
  {
    int n4 = CBQ * 64;
    bcast_rows<<<(n4 + 255) / 256, 256, 0, stream>>>((const float4*)q_t, (float4*)qk, n4, 4);
  }

  // 3) refinement layers
  for (int l = 0; l < 3; ++l) {
    // val = f_scales @ vW[l] + vb[l]   (130560 x 256) — bf16 in/out
    gemm_mfma<ushort, ushort, false><<<dim3(2, 1020), 256, 0, stream>>>(
        fsb, wt + WT_vW + (size_t)l * 65536, vb + l * CD, valb, 256, 256);
    // [off | aw-logits] = qk @ [off_W | attw_W] (8192 x 384)
    gemm_mfma<float, float, false><<<dim3(3, 64), 256, 0, stream>>>(
        qk, wt + WT_oab + (size_t)l * 98304, cbias + l * 384, oabuf, 384, 256);
    // sampling (softmax fused in-kernel)
    msdeform_kernel<<<CBQ / 4, 256, 0, stream>>>(valb, oabuf, ref, attp);
    // o-proj   (8192 x 256)
    gemm_mfma<float, float, false><<<dim3(2, 64), 256, 0, stream>>>(
        attp, wt + WT_oW + (size_t)l * 65536, ob + l * CD, tmp, 256, 256);
    resln_kernel<<<CBQ, 256, 0, stream>>>(tmp, qk, ln1_g + l * CD, ln1_b + l * CD, qk);
    // ffn1 (8192 x 1024, relu, bf16 out), ffn2 (8192 x 256, K=1024, bf16 in)
    gemm_mfma<float, ushort, true><<<dim3(8, 64), 256, 0, stream>>>(
        qk, wt + WT_ffn1 + (size_t)l * 262144, ffn1_b + l * CDFF, hidb, 1024, 256);
    gemm_mfma<ushort, float, false><<<dim3(2, 64), 256, 0, stream>>>(
        hidb, wt + WT_ffn2 + (size_t)l * 262144, ffn2_b + l * CD, tmp, 256, 1024);
    resln_kernel<<<CBQ, 256, 0, stream>>>(tmp, qk, ln2_g + l * CD, ln2_b + l * CD, qk);
  }

  // 4) fusion: cat([qk, q_bcast]) @ fus_W + fus_b
  {
    int n4 = CBQ * 128;
    concat_rows<<<(n4 + 255) / 256, 256, 0, stream>>>((const float4*)qk, (const float4*)q_t,
                                                      (float4*)catb, n4, 4);
  }
  gemm_mfma<float, float, false><<<dim3(2, 64), 256, 0, stream>>>(
      catb, wt + WT_fus, fus_b, attp, 256, 512);  // attp = fused

  // 5) u/s logits
  logits_kernel<<<CBQ / 4, 256, 0, stream>>>(attp, cert_W, cert_b, sc_W, sc_b, out_u, out_s);

  // 6) single-query attention over K=16
  gemm_mfma<float, float, false><<<dim3(2, 4), 256, 0, stream>>>(
      q_t, wt + WT_fq, fq_b, qh, 256, 256);
  gemm_mfma<float, float, false><<<dim3(4, 64), 256, 0, stream>>>(
      attp, wt + WT_fkv, cbias + 1152, kvb, 512, 256);   // [k | v]
  attn_kernel<<<512, 256, 0, stream>>>(qh, kvb, obuf);

  // 7) o = LN(qf + o@fo_W + fo_b)
  gemm_mfma<float, float, false><<<dim3(2, 4), 256, 0, stream>>>(
      obuf, wt + WT_fo, fo_b, t3, 256, 256);
  resln_kernel<<<512, 256, 0, stream>>>(t3, q_t, fln1_g, fln1_b, o1);

  // 8) final FFN + LN
  gemm_mfma<float, ushort, true><<<dim3(8, 4), 256, 0, stream>>>(
      o1, wt + WT_fffn1, fffn1_b, fhidb, 1024, 256);
  gemm_mfma<ushort, float, false><<<dim3(2, 4), 256, 0, stream>>>(
      fhidb, wt + WT_fffn2, fffn2_b, t3, 256, 1024);
  resln_kernel<<<512, 256, 0, stream>>>(t3, o1, fln2_g, fln2_b, o2);

  // 9) out = cat([o2, qf]) @ fin_W + fin_b
  {
    int n4 = 512 * 128;
    concat_rows<<<(n4 + 255) / 256, 256, 0, stream>>>((const float4*)o2, (const float4*)q_t,
                                                      (float4*)catb, n4, 0);
  }
  gemm_mfma<float, float, false><<<dim3(2, 4), 256, 0, stream>>>(
      catb, wt + WT_fin, fin_b, out_main, 256, 512);
}